// Round 4
// baseline (327.045 us; speedup 1.0000x reference)
//
#include <hip/hip_runtime.h>
#include <stdint.h>

#define T_SEQ 2048
#define NH 16
#define HD 64
#define DM 1024
#define BB 4
#define MROWS (BB * T_SEQ)   // 8192

typedef __attribute__((ext_vector_type(8))) __bf16 bf16x8;
typedef __attribute__((ext_vector_type(8))) unsigned short u16x8;
typedef __attribute__((ext_vector_type(4))) unsigned short u16x4;
typedef __attribute__((ext_vector_type(4))) float f32x4;

// Native cast -> compiler emits v_cvt_pk_bf16_f32 (RNE, pairs fuse).
// R4: replaced hand-rolled bit-math RNE (4 VALU ops/value) which blocked
// the cvt_pk path (T12/m240: scalar cast beats hand conversion).
__device__ __forceinline__ unsigned short f2bf(float f) {
  return __builtin_bit_cast(unsigned short, (__bf16)f);
}

__device__ __forceinline__ bf16x8 ld8_f32(const float* __restrict__ p) {
  f32x4 a = *(const f32x4*)p;
  f32x4 b = *(const f32x4*)(p + 4);
  u16x8 u;
#pragma unroll
  for (int i = 0; i < 4; ++i) {
    u[i]     = f2bf(a[i]);
    u[i + 4] = f2bf(b[i]);
  }
  return __builtin_bit_cast(bf16x8, u);
}

__device__ __forceinline__ bf16x8 ld8_bf(const unsigned short* p) {
  return __builtin_bit_cast(bf16x8, *(const u16x8*)p);
}

// 8-aligned LDS read as two b64s (stride-68 layouts are not 16B-aligned)
__device__ __forceinline__ bf16x8 ld8_lds(const unsigned short* p) {
  u16x4 a = *(const u16x4*)p;
  u16x4 b = *(const u16x4*)(p + 4);
  return __builtin_bit_cast(bf16x8,
      __builtin_shufflevector(a, b, 0, 1, 2, 3, 4, 5, 6, 7));
}

__device__ __forceinline__ u16x4 lo4(u16x8 v) {
  return __builtin_shufflevector(v, v, 0, 1, 2, 3);
}
__device__ __forceinline__ u16x4 hi4(u16x8 v) {
  return __builtin_shufflevector(v, v, 4, 5, 6, 7);
}

__device__ __forceinline__ void gload_lds16(const unsigned short* g,
                                            unsigned short* l) {
  __builtin_amdgcn_global_load_lds(
      (const __attribute__((address_space(1))) unsigned int*)g,
      (__attribute__((address_space(3))) unsigned int*)l, 16, 0, 0);
}

// ---------------------------------------------------------------------------
// fp32 -> bf16 elementwise (8 elems/thread).
// ---------------------------------------------------------------------------
__global__ __launch_bounds__(256) void conv_f32_bf16(
    const float* __restrict__ src, unsigned short* __restrict__ dst, int n8) {
  const int i = blockIdx.x * 256 + threadIdx.x;
  if (i < n8)
    *(u16x8*)(dst + (size_t)i * 8) =
        __builtin_bit_cast(u16x8, ld8_f32(src + (size_t)i * 8));
}

// Fused 4-weight conversion: y selects (src,dst). Wk_b/Wv_b/Wq_b contiguous.
__global__ __launch_bounds__(256) void conv_w4(
    const float* __restrict__ s0, const float* __restrict__ s1,
    const float* __restrict__ s2, const float* __restrict__ s3,
    unsigned short* __restrict__ d012, unsigned short* __restrict__ d3,
    int n8) {
  const int y = blockIdx.y;
  const float* src = (y == 0) ? s0 : (y == 1) ? s1 : (y == 2) ? s2 : s3;
  unsigned short* dst = (y < 3) ? d012 + (size_t)y * DM * DM : d3;
  const int i = blockIdx.x * 256 + threadIdx.x;
  if (i < n8)
    *(u16x8*)(dst + (size_t)i * 8) =
        __builtin_bit_cast(u16x8, ld8_f32(src + (size_t)i * 8));
}

// ---------------------------------------------------------------------------
// m97-style bf16 GEMM: C = A[M,K] @ B[N,K]^T. 128x128 tile, BK=64 via two
// BK=32 buffer pairs. Shape is fixed M=8192, N=1024, K=1024, grid 512.
//
// R4: XCD-aware block remap (T1). Default x-fastest dispatch puts XCD =
// lin%8 = COLUMN index -> every XCD streams all 16MB of A through its 4MB
// L2 (zero L2 reuse of A; 256MB/GEMM staging traffic at ~5.4 TB/s was the
// measured limiter). Remap: XCD k owns row-panels 8k..8k+7 and walks each
// panel's 8 column tiles consecutively -> per-XCD L2 working set = 256KB
// A-panel + 2MB B; A read once from HBM chip-wide. Bijective on 512 blocks.
// ---------------------------------------------------------------------------
template <int MODE>
__global__ __launch_bounds__(256) void gemm128(
    const unsigned short* __restrict__ A, const unsigned short* __restrict__ B,
    void* __restrict__ Cv, int M, int N, int K) {
  __shared__ __align__(16) unsigned short As[2][128 * 32];
  __shared__ __align__(16) unsigned short Bs[2][128 * 32];

  const int t = threadIdx.x;
  const int lane = t & 63, wave = t >> 6;
  const int lin = (int)(blockIdx.x + gridDim.x * blockIdx.y);  // 0..511
  const int xcd = lin & 7, slot = lin >> 3;                    // slot 0..63
  const int m0 = (xcd * 8 + (slot >> 3)) * 128;                // row panel
  const int n0 = (slot & 7) * 128;                             // col tile

  const int srow = t >> 2;
  const int scol = (t & 3) * 8;
  const unsigned short* ga0 = A + (size_t)(m0 + srow) * K + scol;
  const unsigned short* ga1 = A + (size_t)(m0 + 64 + srow) * K + scol;
  const unsigned short* gb0 = B + (size_t)(n0 + srow) * K + scol;
  const unsigned short* gb1 = B + (size_t)(n0 + 64 + srow) * K + scol;
  const int lo0 = (wave * 16) * 32, lo1 = (64 + wave * 16) * 32;

  const int mw = (wave >> 1) * 64, nw = (wave & 1) * 64;
  const int fr = lane & 15, fq = (lane >> 4) * 8;

  f32x4 acc[4][4];
#pragma unroll
  for (int i = 0; i < 4; ++i)
#pragma unroll
    for (int j = 0; j < 4; ++j) acc[i][j] = (f32x4){0.f, 0.f, 0.f, 0.f};

  for (int k0 = 0; k0 < K; k0 += 64) {
    __syncthreads();
    gload_lds16(ga0 + k0, &As[0][lo0]);
    gload_lds16(ga1 + k0, &As[0][lo1]);
    gload_lds16(gb0 + k0, &Bs[0][lo0]);
    gload_lds16(gb1 + k0, &Bs[0][lo1]);
    gload_lds16(ga0 + k0 + 32, &As[1][lo0]);
    gload_lds16(ga1 + k0 + 32, &As[1][lo1]);
    gload_lds16(gb0 + k0 + 32, &Bs[1][lo0]);
    gload_lds16(gb1 + k0 + 32, &Bs[1][lo1]);
    __syncthreads();

#pragma unroll
    for (int ks = 0; ks < 2; ++ks) {
      bf16x8 af[4], bfr[4];
#pragma unroll
      for (int i = 0; i < 4; ++i)
        af[i] = ld8_bf(&As[ks][(mw + i * 16 + fr) * 32 + fq]);
#pragma unroll
      for (int j = 0; j < 4; ++j)
        bfr[j] = ld8_bf(&Bs[ks][(nw + j * 16 + fr) * 32 + fq]);
#pragma unroll
      for (int i = 0; i < 4; ++i)
#pragma unroll
        for (int j = 0; j < 4; ++j)
          acc[i][j] = __builtin_amdgcn_mfma_f32_16x16x32_bf16(
              af[i], bfr[j], acc[i][j], 0, 0, 0);
    }
  }

  const int orow = (lane >> 4) * 4, ocol = lane & 15;
#pragma unroll
  for (int i = 0; i < 4; ++i)
#pragma unroll
    for (int j = 0; j < 4; ++j) {
      if constexpr (MODE == 2) {
        // transposed pack: m -> (b,t), n -> (h,d); 4 r values = consecutive t
        const int mb = m0 + mw + i * 16 + orow;
        const int n = n0 + nw + j * 16 + ocol;
        u16x4 pk;
#pragma unroll
        for (int r = 0; r < 4; ++r) pk[r] = f2bf(acc[i][j][r]);
        unsigned short* dst = (unsigned short*)Cv +
            ((size_t)((mb >> 11) * NH + (n >> 6)) * HD + (n & 63)) * T_SEQ +
            (mb & 2047);
        *(u16x4*)dst = pk;
      } else {
#pragma unroll
        for (int r = 0; r < 4; ++r) {
          const size_t idx = (size_t)(m0 + mw + i * 16 + orow + r) * N +
                             (n0 + nw + j * 16 + ocol);
          if constexpr (MODE == 1)
            ((float*)Cv)[idx] = acc[i][j][r];
          else
            ((unsigned short*)Cv)[idx] = f2bf(acc[i][j][r]);
        }
      }
    }
}

// ---------------------------------------------------------------------------
// MFMA flash attention v2 (causal). Paired q-tiles {15-pi, pi} per block for
// uniform work. S^T formulation: S^T = K @ Q^T so softmax is column-wise
// (2 shuffles), P packs as b64 along keys. V pre-transposed (Vt[b][h][d][t]).
// LDS stride 68 u16 (2-way, free). K/V double-buffered, one barrier/tile.
//
// R4: FUSED pair processing — attn is VALU-bound (R3: VALUBusy 48% vs
// MfmaUtil 15%), so (a) K-frag/V-frag LDS reads are shared by both subtiles
// (8 MFMA per frag-pair load instead of 4), (b) P->bf16 packing uses the
// native cvt_pk path (f2bf rewrite). Both P tiles live in LDS (pA/pB),
// LDS ~70KB -> still 2 blocks/CU (grid is 512 = 2/CU anyway).
// launch_bounds(256,2) = 256-VGPR budget (R1 lesson: tighter budget spilled).
// ---------------------------------------------------------------------------
#define ASTR 68

__global__ __launch_bounds__(256, 2) void attn_flash2(
    const unsigned short* Qw, const unsigned short* __restrict__ Kw,
    const unsigned short* __restrict__ Vt, unsigned short* Ow) {
  __shared__ __align__(16) unsigned short k_lds[2][64][ASTR];
  __shared__ __align__(16) unsigned short vt_lds[2][64][ASTR];
  __shared__ __align__(16) unsigned short pA_lds[4][32][ASTR];
  __shared__ __align__(16) unsigned short pB_lds[4][32][ASTR];
  __shared__ float alA_lds[4][32];
  __shared__ float alB_lds[4][32];
  __shared__ float l_lds[4][32];

  const int tid = threadIdx.x, lane = tid & 63, wave = tid >> 6;
  const int c16 = lane & 15, quad = lane >> 4;
  const int b = blockIdx.z, h = blockIdx.y;
  const int pi = blockIdx.x;            // pair index 0..7
  const int qb0A = (15 - pi) * 128;     // heavy
  const int qb0B = pi * 128;            // light
  const size_t rkbase = (size_t)b * T_SEQ * DM + (size_t)h * HD;
  const size_t vtbase = (size_t)(b * NH + h) * HD * T_SEQ;

  const int q_loA = qb0A + wave * 32;
  const int q_loB = qb0B + wave * 32;

  // Q B-frags (resident): B[n=q][k=d], d = quad*8 + kf*32
  bf16x8 qfA[2][2], qfB[2][2];
#pragma unroll
  for (int nf = 0; nf < 2; ++nf) {
    const unsigned short* qpA =
        Qw + rkbase + (size_t)(q_loA + nf * 16 + c16) * DM + quad * 8;
    qfA[nf][0] = ld8_bf(qpA);
    qfA[nf][1] = ld8_bf(qpA + 32);
    const unsigned short* qpB =
        Qw + rkbase + (size_t)(q_loB + nf * 16 + c16) * DM + quad * 8;
    qfB[nf][0] = ld8_bf(qpB);
    qfB[nf][1] = ld8_bf(qpB + 32);
  }

  f32x4 oA[2][4], oB[2][4];
#pragma unroll
  for (int nf = 0; nf < 2; ++nf)
#pragma unroll
    for (int j = 0; j < 4; ++j) {
      oA[nf][j] = (f32x4){0.f, 0.f, 0.f, 0.f};
      oB[nf][j] = (f32x4){0.f, 0.f, 0.f, 0.f};
    }
  float mA[2] = {-3.0e38f, -3.0e38f}, lA[2] = {0.f, 0.f};
  float mB[2] = {-3.0e38f, -3.0e38f}, lB[2] = {0.f, 0.f};

  const int srow = tid >> 2;          // 0..63 (key idx for K, d idx for Vt)
  const int scol = (tid & 3) * 16;    // 0/16/32/48
  const int ntiles = (qb0A + 191) >> 6;     // heavy bound covers light
  const int ntA_w = (q_loA + 95) >> 6;
  const int ntB_w = (q_loB + 95) >> 6;

  const unsigned short* kp0 = Kw + rkbase + (size_t)srow * DM + scol;
  const unsigned short* vp0 = Vt + vtbase + (size_t)srow * T_SEQ + scol;

  // mask+scale then online-softmax for one subtile's S^T block
  auto mask_sm = [&](f32x4 (&s)[4][2], float* m_r, float* l_r, const int q_lo,
                     const int kb0, unsigned short (*pl)[ASTR],
                     float* al_row) {
    if (kb0 + 63 > q_lo) {
#pragma unroll
      for (int mf = 0; mf < 4; ++mf) {
        const int key0 = kb0 + mf * 16 + quad * 4;
#pragma unroll
        for (int nf = 0; nf < 2; ++nf) {
          const int qg = q_lo + nf * 16 + c16;
#pragma unroll
          for (int r = 0; r < 4; ++r)
            s[mf][nf][r] =
                (key0 + r <= qg) ? s[mf][nf][r] * 0.125f : -3.0e38f;
        }
      }
    } else {
#pragma unroll
      for (int mf = 0; mf < 4; ++mf)
#pragma unroll
        for (int nf = 0; nf < 2; ++nf)
#pragma unroll
          for (int r = 0; r < 4; ++r) s[mf][nf][r] *= 0.125f;
    }
#pragma unroll
    for (int nf = 0; nf < 2; ++nf) {
      float mx = -3.0e38f;
#pragma unroll
      for (int mf = 0; mf < 4; ++mf)
#pragma unroll
        for (int r = 0; r < 4; ++r) mx = fmaxf(mx, s[mf][nf][r]);
      mx = fmaxf(mx, __shfl_xor(mx, 16, 64));
      mx = fmaxf(mx, __shfl_xor(mx, 32, 64));
      const float m_new = fmaxf(m_r[nf], mx);
      const float al = __expf(m_r[nf] - m_new);
      m_r[nf] = m_new;
      float ps = 0.f;
#pragma unroll
      for (int mf = 0; mf < 4; ++mf) {
        u16x4 pk;
#pragma unroll
        for (int r = 0; r < 4; ++r) {
          const float e = __expf(s[mf][nf][r] - m_new);
          ps += e;
          pk[r] = f2bf(e);
        }
        *(u16x4*)&pl[nf * 16 + c16][mf * 16 + quad * 4] = pk;
      }
      ps += __shfl_xor(ps, 16, 64);
      ps += __shfl_xor(ps, 32, 64);
      l_r[nf] = l_r[nf] * al + ps;
      if (quad == 0) al_row[nf * 16 + c16] = al;
    }
  };

  auto rescale = [&](f32x4 (&o)[2][4], const float* al_row) {
#pragma unroll
    for (int nf = 0; nf < 2; ++nf) {
      float alr[4];
#pragma unroll
      for (int r = 0; r < 4; ++r)
        alr[r] = al_row[nf * 16 + quad * 4 + r];
#pragma unroll
      for (int j = 0; j < 4; ++j)
#pragma unroll
        for (int r = 0; r < 4; ++r) o[nf][j][r] *= alr[r];
    }
  };

  // prologue: stage tile 0 into buf 0
  {
    u16x8 ka = *(const u16x8*)kp0;
    u16x8 kc = *(const u16x8*)(kp0 + 8);
    u16x8 va = *(const u16x8*)vp0;
    u16x8 vc = *(const u16x8*)(vp0 + 8);
    *(u16x4*)&k_lds[0][srow][scol]       = lo4(ka);
    *(u16x4*)&k_lds[0][srow][scol + 4]   = hi4(ka);
    *(u16x4*)&k_lds[0][srow][scol + 8]   = lo4(kc);
    *(u16x4*)&k_lds[0][srow][scol + 12]  = hi4(kc);
    *(u16x4*)&vt_lds[0][srow][scol]      = lo4(va);
    *(u16x4*)&vt_lds[0][srow][scol + 4]  = hi4(va);
    *(u16x4*)&vt_lds[0][srow][scol + 8]  = lo4(vc);
    *(u16x4*)&vt_lds[0][srow][scol + 12] = hi4(vc);
  }
  __syncthreads();

  int cur = 0;
  for (int t = 0; t < ntiles; ++t) {
    const int kb0 = t * 64;
    const bool pf = (t + 1 < ntiles);
    u16x8 ka, kc, va, vc;
    if (pf) {  // issue next-tile loads; consumed by ds_write after compute
      const unsigned short* kp = kp0 + (size_t)(kb0 + 64) * DM;
      ka = *(const u16x8*)kp;
      kc = *(const u16x8*)(kp + 8);
      const unsigned short* vp = vp0 + (kb0 + 64);
      va = *(const u16x8*)vp;
      vc = *(const u16x8*)(vp + 8);
    }

    if (t < ntA_w) {
      const bool doB = (t < ntB_w);  // doB implies doA
      // ---- S^T = K @ Q^T for both subtiles (K-frags shared) ----
      f32x4 sA[4][2], sB[4][2];
      __builtin_amdgcn_s_setprio(1);
#pragma unroll
      for (int mf = 0; mf < 4; ++mf) {
        const unsigned short* kr = &k_lds[cur][mf * 16 + c16][quad * 8];
        const bf16x8 k0 = ld8_lds(kr);
        const bf16x8 k1 = ld8_lds(kr + 32);
#pragma unroll
        for (int nf = 0; nf < 2; ++nf) {
          f32x4 a = {0.f, 0.f, 0.f, 0.f};
          a = __builtin_amdgcn_mfma_f32_16x16x32_bf16(k0, qfA[nf][0], a, 0, 0, 0);
          a = __builtin_amdgcn_mfma_f32_16x16x32_bf16(k1, qfA[nf][1], a, 0, 0, 0);
          sA[mf][nf] = a;
        }
        if (doB) {
#pragma unroll
          for (int nf = 0; nf < 2; ++nf) {
            f32x4 a = {0.f, 0.f, 0.f, 0.f};
            a = __builtin_amdgcn_mfma_f32_16x16x32_bf16(k0, qfB[nf][0], a, 0, 0, 0);
            a = __builtin_amdgcn_mfma_f32_16x16x32_bf16(k1, qfB[nf][1], a, 0, 0, 0);
            sB[mf][nf] = a;
          }
        }
      }
      __builtin_amdgcn_s_setprio(0);

      // ---- mask + online softmax (A, then B) ----
      mask_sm(sA, mA, lA, q_loA, kb0, pA_lds[wave], alA_lds[wave]);
      if (doB) mask_sm(sB, mB, lB, q_loB, kb0, pB_lds[wave], alB_lds[wave]);
      __threadfence_block();  // drain this wave's LDS writes (p, alpha)

      // ---- rescale O ----
      rescale(oA, alA_lds[wave]);
      if (doB) rescale(oB, alB_lds[wave]);

      // ---- O += P @ V for both subtiles (V-frags shared) ----
      bf16x8 pfA[2][2], pfB[2][2];
#pragma unroll
      for (int nf = 0; nf < 2; ++nf) {
        const unsigned short* pw = &pA_lds[wave][nf * 16 + c16][quad * 8];
        pfA[nf][0] = ld8_lds(pw);
        pfA[nf][1] = ld8_lds(pw + 32);
      }
      if (doB) {
#pragma unroll
        for (int nf = 0; nf < 2; ++nf) {
          const unsigned short* pw = &pB_lds[wave][nf * 16 + c16][quad * 8];
          pfB[nf][0] = ld8_lds(pw);
          pfB[nf][1] = ld8_lds(pw + 32);
        }
      }
      __builtin_amdgcn_s_setprio(1);
#pragma unroll
      for (int j = 0; j < 4; ++j) {
        const unsigned short* vr = &vt_lds[cur][j * 16 + c16][quad * 8];
        const bf16x8 v0 = ld8_lds(vr);
        const bf16x8 v1 = ld8_lds(vr + 32);
#pragma unroll
        for (int nf = 0; nf < 2; ++nf) {
          oA[nf][j] = __builtin_amdgcn_mfma_f32_16x16x32_bf16(pfA[nf][0], v0,
                                                              oA[nf][j], 0, 0, 0);
          oA[nf][j] = __builtin_amdgcn_mfma_f32_16x16x32_bf16(pfA[nf][1], v1,
                                                              oA[nf][j], 0, 0, 0);
        }
        if (doB) {
#pragma unroll
          for (int nf = 0; nf < 2; ++nf) {
            oB[nf][j] = __builtin_amdgcn_mfma_f32_16x16x32_bf16(
                pfB[nf][0], v0, oB[nf][j], 0, 0, 0);
            oB[nf][j] = __builtin_amdgcn_mfma_f32_16x16x32_bf16(
                pfB[nf][1], v1, oB[nf][j], 0, 0, 0);
          }
        }
      }
      __builtin_amdgcn_s_setprio(0);
    }

    if (pf) {
      const int nb = cur ^ 1;
      *(u16x4*)&k_lds[nb][srow][scol]       = lo4(ka);
      *(u16x4*)&k_lds[nb][srow][scol + 4]   = hi4(ka);
      *(u16x4*)&k_lds[nb][srow][scol + 8]   = lo4(kc);
      *(u16x4*)&k_lds[nb][srow][scol + 12]  = hi4(kc);
      *(u16x4*)&vt_lds[nb][srow][scol]      = lo4(va);
      *(u16x4*)&vt_lds[nb][srow][scol + 4]  = hi4(va);
      *(u16x4*)&vt_lds[nb][srow][scol + 8]  = lo4(vc);
      *(u16x4*)&vt_lds[nb][srow][scol + 12] = hi4(vc);
      __syncthreads();
      cur = nb;
    }
  }

  // ---- epilogue: O/l, C-layout scatter (q = row), A then B ----
  auto epi = [&](f32x4 (&o)[2][4], float (&l_r)[2], const int q_lo) {
    if (quad == 0) {
      l_lds[wave][c16] = l_r[0];
      l_lds[wave][16 + c16] = l_r[1];
    }
    __threadfence_block();
#pragma unroll
    for (int nf = 0; nf < 2; ++nf)
#pragma unroll
      for (int r = 0; r < 4; ++r) {
        const int qg = q_lo + nf * 16 + quad * 4 + r;
        const float inv = 1.0f / l_lds[wave][nf * 16 + quad * 4 + r];
        unsigned short* orow = Ow + rkbase + (size_t)qg * DM;
#pragma unroll
        for (int j = 0; j < 4; ++j)
          orow[j * 16 + c16] = f2bf(o[nf][j][r] * inv);
      }
  };
  epi(oA, lA, q_loA);
  __threadfence_block();
  epi(oB, lB, q_loB);
}

extern "C" void kernel_launch(void* const* d_in, const int* in_sizes, int n_in,
                              void* d_out, int out_size, void* d_ws, size_t ws_size,
                              hipStream_t stream) {
  const float* x_q  = (const float*)d_in[0];
  const float* x_kv = (const float*)d_in[1];
  const float* Wq   = (const float*)d_in[2];
  const float* Wk   = (const float*)d_in[3];
  const float* Wv   = (const float*)d_in[4];
  const float* Wo   = (const float*)d_in[5];
  float* out = (float*)d_out;

  // d_out doubles as early scratch; final GEMM reads only from ws.
  unsigned short* scr  = (unsigned short*)d_out;
  unsigned short* Sx   = scr;                          // x bf16 slot
  unsigned short* Wk_b = scr + (size_t)MROWS * DM;
  unsigned short* Wv_b = Wk_b + (size_t)DM * DM;
  unsigned short* Wq_b = Wv_b + (size_t)DM * DM;

  unsigned short* qb   = (unsigned short*)d_ws;
  unsigned short* kb   = qb + (size_t)MROWS * DM;
  unsigned short* vtb  = kb + (size_t)MROWS * DM;      // Vt[b][h][d][t]
  unsigned short* Wo_b = vtb + (size_t)MROWS * DM;

  const int nW8 = DM * DM / 8;
  const int nX8 = MROWS * DM / 8;

  conv_w4<<<dim3(nW8 / 256, 4), 256, 0, stream>>>(Wk, Wv, Wq, Wo, Wk_b, Wo_b,
                                                  nW8);
  conv_f32_bf16<<<nX8 / 256, 256, 0, stream>>>(x_kv, Sx, nX8);

  dim3 gg(DM / 128, MROWS / 128);  // (8, 64) -> in-kernel XCD remap
  gemm128<0><<<gg, 256, 0, stream>>>(Sx, Wk_b, kb, MROWS, DM, DM);
  gemm128<2><<<gg, 256, 0, stream>>>(Sx, Wv_b, vtb, MROWS, DM, DM);
  conv_f32_bf16<<<nX8 / 256, 256, 0, stream>>>(x_q, Sx, nX8);
  gemm128<0><<<gg, 256, 0, stream>>>(Sx, Wq_b, qb, MROWS, DM, DM);
  attn_flash2<<<dim3(8, NH, BB), 256, 0, stream>>>(qb, kb, vtb, qb);
  gemm128<1><<<gg, 256, 0, stream>>>(qb, Wo_b, out, MROWS, DM, DM);
}

// Round 5
// 302.928 us; speedup vs baseline: 1.0796x; 1.0796x over previous
//
#include <hip/hip_runtime.h>
#include <stdint.h>

#define T_SEQ 2048
#define NH 16
#define HD 64
#define DM 1024
#define BB 4
#define MROWS (BB * T_SEQ)   // 8192

typedef __attribute__((ext_vector_type(8))) __bf16 bf16x8;
typedef __attribute__((ext_vector_type(8))) unsigned short u16x8;
typedef __attribute__((ext_vector_type(4))) unsigned short u16x4;
typedef __attribute__((ext_vector_type(4))) float f32x4;

// Native cast -> compiler emits v_cvt_pk_bf16_f32 (RNE, pairs fuse).
__device__ __forceinline__ unsigned short f2bf(float f) {
  return __builtin_bit_cast(unsigned short, (__bf16)f);
}

__device__ __forceinline__ bf16x8 ld8_f32(const float* __restrict__ p) {
  f32x4 a = *(const f32x4*)p;
  f32x4 b = *(const f32x4*)(p + 4);
  u16x8 u;
#pragma unroll
  for (int i = 0; i < 4; ++i) {
    u[i]     = f2bf(a[i]);
    u[i + 4] = f2bf(b[i]);
  }
  return __builtin_bit_cast(bf16x8, u);
}

__device__ __forceinline__ bf16x8 ld8_bf(const unsigned short* p) {
  return __builtin_bit_cast(bf16x8, *(const u16x8*)p);
}

// 8-aligned LDS read as two b64s (stride-68 layouts are not 16B-aligned)
__device__ __forceinline__ bf16x8 ld8_lds(const unsigned short* p) {
  u16x4 a = *(const u16x4*)p;
  u16x4 b = *(const u16x4*)(p + 4);
  return __builtin_bit_cast(bf16x8,
      __builtin_shufflevector(a, b, 0, 1, 2, 3, 4, 5, 6, 7));
}

__device__ __forceinline__ u16x4 lo4(u16x8 v) {
  return __builtin_shufflevector(v, v, 0, 1, 2, 3);
}
__device__ __forceinline__ u16x4 hi4(u16x8 v) {
  return __builtin_shufflevector(v, v, 4, 5, 6, 7);
}

__device__ __forceinline__ void gload_lds16(const unsigned short* g,
                                            unsigned short* l) {
  __builtin_amdgcn_global_load_lds(
      (const __attribute__((address_space(1))) unsigned int*)g,
      (__attribute__((address_space(3))) unsigned int*)l, 16, 0, 0);
}

// ---------------------------------------------------------------------------
// fp32 -> bf16 elementwise (8 elems/thread).
// ---------------------------------------------------------------------------
__global__ __launch_bounds__(256) void conv_f32_bf16(
    const float* __restrict__ src, unsigned short* __restrict__ dst, int n8) {
  const int i = blockIdx.x * 256 + threadIdx.x;
  if (i < n8)
    *(u16x8*)(dst + (size_t)i * 8) =
        __builtin_bit_cast(u16x8, ld8_f32(src + (size_t)i * 8));
}

// Fused 4-weight conversion: y selects (src,dst). Wk_b/Wv_b/Wq_b contiguous.
__global__ __launch_bounds__(256) void conv_w4(
    const float* __restrict__ s0, const float* __restrict__ s1,
    const float* __restrict__ s2, const float* __restrict__ s3,
    unsigned short* __restrict__ d012, unsigned short* __restrict__ d3,
    int n8) {
  const int y = blockIdx.y;
  const float* src = (y == 0) ? s0 : (y == 1) ? s1 : (y == 2) ? s2 : s3;
  unsigned short* dst = (y < 3) ? d012 + (size_t)y * DM * DM : d3;
  const int i = blockIdx.x * 256 + threadIdx.x;
  if (i < n8)
    *(u16x8*)(dst + (size_t)i * 8) =
        __builtin_bit_cast(u16x8, ld8_f32(src + (size_t)i * 8));
}

// ---------------------------------------------------------------------------
// m97-style bf16 GEMM: C = A[M,K] @ B[N,K]^T. 128x128 tile, BK=64 via two
// BK=32 buffer pairs. XCD remap generalized to runtime nx (R4's was
// shape-specific). MODE 0: bf16 row-major (stride N). MODE 1: f32 row-major.
// MODE 2: bf16 transposed to Vt[b][h][d][t]. MODE 3 (R5): fused K+V
// projection, N=2048 — block-uniform epilogue branch: n0 < DM writes
// kb-layout (stride DM) to Cv, n0 >= DM writes Vt-layout to Cv2.
// R5 rationale: GEMMs were occupancy-bound (512 blocks = 2 blocks/CU = 2
// waves/SIMD; barrier drains exposed). Fused KV = 1024 blocks = 4/CU.
// ---------------------------------------------------------------------------
template <int MODE>
__global__ __launch_bounds__(256) void gemm128(
    const unsigned short* __restrict__ A, const unsigned short* __restrict__ B,
    void* __restrict__ Cv, void* __restrict__ Cv2, int M, int N, int K) {
  __shared__ __align__(16) unsigned short As[2][128 * 32];
  __shared__ __align__(16) unsigned short Bs[2][128 * 32];

  const int t = threadIdx.x;
  const int lane = t & 63, wave = t >> 6;
  const int lin = (int)(blockIdx.x + gridDim.x * blockIdx.y);
  const int nx = N >> 7;                       // n-tiles
  const int mpx = (M >> 7) >> 3;               // m-panels per XCD
  const int xcd = lin & 7, slot = lin >> 3;
  const int m0 = (xcd * mpx + slot / nx) * 128;
  const int n0 = (slot % nx) * 128;

  const int srow = t >> 2;
  const int scol = (t & 3) * 8;
  const unsigned short* ga0 = A + (size_t)(m0 + srow) * K + scol;
  const unsigned short* ga1 = A + (size_t)(m0 + 64 + srow) * K + scol;
  const unsigned short* gb0 = B + (size_t)(n0 + srow) * K + scol;
  const unsigned short* gb1 = B + (size_t)(n0 + 64 + srow) * K + scol;
  const int lo0 = (wave * 16) * 32, lo1 = (64 + wave * 16) * 32;

  const int mw = (wave >> 1) * 64, nw = (wave & 1) * 64;
  const int fr = lane & 15, fq = (lane >> 4) * 8;

  f32x4 acc[4][4];
#pragma unroll
  for (int i = 0; i < 4; ++i)
#pragma unroll
    for (int j = 0; j < 4; ++j) acc[i][j] = (f32x4){0.f, 0.f, 0.f, 0.f};

  for (int k0 = 0; k0 < K; k0 += 64) {
    __syncthreads();
    gload_lds16(ga0 + k0, &As[0][lo0]);
    gload_lds16(ga1 + k0, &As[0][lo1]);
    gload_lds16(gb0 + k0, &Bs[0][lo0]);
    gload_lds16(gb1 + k0, &Bs[0][lo1]);
    gload_lds16(ga0 + k0 + 32, &As[1][lo0]);
    gload_lds16(ga1 + k0 + 32, &As[1][lo1]);
    gload_lds16(gb0 + k0 + 32, &Bs[1][lo0]);
    gload_lds16(gb1 + k0 + 32, &Bs[1][lo1]);
    __syncthreads();

#pragma unroll
    for (int ks = 0; ks < 2; ++ks) {
      bf16x8 af[4], bfr[4];
#pragma unroll
      for (int i = 0; i < 4; ++i)
        af[i] = ld8_bf(&As[ks][(mw + i * 16 + fr) * 32 + fq]);
#pragma unroll
      for (int j = 0; j < 4; ++j)
        bfr[j] = ld8_bf(&Bs[ks][(nw + j * 16 + fr) * 32 + fq]);
#pragma unroll
      for (int i = 0; i < 4; ++i)
#pragma unroll
        for (int j = 0; j < 4; ++j)
          acc[i][j] = __builtin_amdgcn_mfma_f32_16x16x32_bf16(
              af[i], bfr[j], acc[i][j], 0, 0, 0);
    }
  }

  const int orow = (lane >> 4) * 4, ocol = lane & 15;
  const bool kv_lo = (MODE == 3) && (n0 < DM);  // block-uniform
#pragma unroll
  for (int i = 0; i < 4; ++i)
#pragma unroll
    for (int j = 0; j < 4; ++j) {
      if constexpr (MODE == 2) {
        // transposed pack: m -> (b,t), n -> (h,d); 4 r values = consecutive t
        const int mb = m0 + mw + i * 16 + orow;
        const int n = n0 + nw + j * 16 + ocol;
        u16x4 pk;
#pragma unroll
        for (int r = 0; r < 4; ++r) pk[r] = f2bf(acc[i][j][r]);
        unsigned short* dst = (unsigned short*)Cv +
            ((size_t)((mb >> 11) * NH + (n >> 6)) * HD + (n & 63)) * T_SEQ +
            (mb & 2047);
        *(u16x4*)dst = pk;
      } else if constexpr (MODE == 3) {
        const int mb = m0 + mw + i * 16 + orow;
        const int n = n0 + nw + j * 16 + ocol;
        if (kv_lo) {  // K path: bf16 row-major, stride DM
#pragma unroll
          for (int r = 0; r < 4; ++r)
            ((unsigned short*)Cv)[(size_t)(mb + r) * DM + n] =
                f2bf(acc[i][j][r]);
        } else {      // V path: Vt[b][h][d][t]
          const int nv = n - DM;
          u16x4 pk;
#pragma unroll
          for (int r = 0; r < 4; ++r) pk[r] = f2bf(acc[i][j][r]);
          unsigned short* dst = (unsigned short*)Cv2 +
              ((size_t)((mb >> 11) * NH + (nv >> 6)) * HD + (nv & 63)) *
                  T_SEQ +
              (mb & 2047);
          *(u16x4*)dst = pk;
        }
      } else {
#pragma unroll
        for (int r = 0; r < 4; ++r) {
          const size_t idx = (size_t)(m0 + mw + i * 16 + orow + r) * N +
                             (n0 + nw + j * 16 + ocol);
          if constexpr (MODE == 1)
            ((float*)Cv)[idx] = acc[i][j][r];
          else
            ((unsigned short*)Cv)[idx] = f2bf(acc[i][j][r]);
        }
      }
    }
}

// ---------------------------------------------------------------------------
// MFMA flash attention v2 (causal). R3 structure (R4's fused-pair variant
// regressed: longer serial dep chains at 2 waves/SIMD). Paired q-tiles
// {15-pi, pi} per block for uniform work. S^T = K @ Q^T; V pre-transposed
// (Vt[b][h][d][t]). LDS stride 68 u16. K/V double-buffered, 1 barrier/tile.
// launch_bounds(256,2) = 256-VGPR budget (R1: tighter budget spilled).
// ---------------------------------------------------------------------------
#define ASTR 68

__global__ __launch_bounds__(256, 2) void attn_flash2(
    const unsigned short* Qw, const unsigned short* __restrict__ Kw,
    const unsigned short* __restrict__ Vt, unsigned short* Ow) {
  __shared__ __align__(16) unsigned short k_lds[2][64][ASTR];
  __shared__ __align__(16) unsigned short vt_lds[2][64][ASTR];
  __shared__ __align__(16) unsigned short p_lds[4][32][ASTR];
  __shared__ float alpha_lds[4][32];
  __shared__ float l_lds[4][32];

  const int tid = threadIdx.x, lane = tid & 63, wave = tid >> 6;
  const int c16 = lane & 15, quad = lane >> 4;
  const int b = blockIdx.z, h = blockIdx.y;
  const int pi = blockIdx.x;            // pair index 0..7
  const int qb0A = (15 - pi) * 128;     // heavy
  const int qb0B = pi * 128;            // light
  const size_t rkbase = (size_t)b * T_SEQ * DM + (size_t)h * HD;
  const size_t vtbase = (size_t)(b * NH + h) * HD * T_SEQ;

  const int q_loA = qb0A + wave * 32;
  const int q_loB = qb0B + wave * 32;

  // Q B-frags (resident): B[n=q][k=d], d = quad*8 + kf*32
  bf16x8 qfA[2][2], qfB[2][2];
#pragma unroll
  for (int nf = 0; nf < 2; ++nf) {
    const unsigned short* qpA =
        Qw + rkbase + (size_t)(q_loA + nf * 16 + c16) * DM + quad * 8;
    qfA[nf][0] = ld8_bf(qpA);
    qfA[nf][1] = ld8_bf(qpA + 32);
    const unsigned short* qpB =
        Qw + rkbase + (size_t)(q_loB + nf * 16 + c16) * DM + quad * 8;
    qfB[nf][0] = ld8_bf(qpB);
    qfB[nf][1] = ld8_bf(qpB + 32);
  }

  f32x4 oA[2][4], oB[2][4];
#pragma unroll
  for (int nf = 0; nf < 2; ++nf)
#pragma unroll
    for (int j = 0; j < 4; ++j) {
      oA[nf][j] = (f32x4){0.f, 0.f, 0.f, 0.f};
      oB[nf][j] = (f32x4){0.f, 0.f, 0.f, 0.f};
    }
  float mA[2] = {-3.0e38f, -3.0e38f}, lA[2] = {0.f, 0.f};
  float mB[2] = {-3.0e38f, -3.0e38f}, lB[2] = {0.f, 0.f};

  const int srow = tid >> 2;          // 0..63 (key idx for K, d idx for Vt)
  const int scol = (tid & 3) * 16;    // 0/16/32/48
  const int ntiles = (qb0A + 191) >> 6;     // heavy bound covers light
  const int ntA_w = (q_loA + 95) >> 6;
  const int ntB_w = (q_loB + 95) >> 6;

  const unsigned short* kp0 = Kw + rkbase + (size_t)srow * DM + scol;
  const unsigned short* vp0 = Vt + vtbase + (size_t)srow * T_SEQ + scol;

  // per-subtile compute: S^T -> online softmax -> rescale -> PV
  auto subtile = [&](const bf16x8 (&qf)[2][2], f32x4 (&o)[2][4],
                     float (&m_r)[2], float (&l_r)[2], const int q_lo,
                     const int kb0, const int bi) {
    // ---- S^T = K @ Q^T : D[m=key][n=q] ----
    f32x4 s[4][2];
    __builtin_amdgcn_s_setprio(1);
#pragma unroll
    for (int mf = 0; mf < 4; ++mf) {
      const unsigned short* kr = &k_lds[bi][mf * 16 + c16][quad * 8];
      const bf16x8 k0 = ld8_lds(kr);
      const bf16x8 k1 = ld8_lds(kr + 32);
#pragma unroll
      for (int nf = 0; nf < 2; ++nf) {
        f32x4 a = {0.f, 0.f, 0.f, 0.f};
        a = __builtin_amdgcn_mfma_f32_16x16x32_bf16(k0, qf[nf][0], a, 0, 0, 0);
        a = __builtin_amdgcn_mfma_f32_16x16x32_bf16(k1, qf[nf][1], a, 0, 0, 0);
        s[mf][nf] = a;
      }
    }
    __builtin_amdgcn_s_setprio(0);
    // scale + causal mask: key = kb0+mf*16+quad*4+r, q = q_lo+nf*16+c16
    if (kb0 + 63 > q_lo) {
#pragma unroll
      for (int mf = 0; mf < 4; ++mf) {
        const int key0 = kb0 + mf * 16 + quad * 4;
#pragma unroll
        for (int nf = 0; nf < 2; ++nf) {
          const int qg = q_lo + nf * 16 + c16;
#pragma unroll
          for (int r = 0; r < 4; ++r)
            s[mf][nf][r] =
                (key0 + r <= qg) ? s[mf][nf][r] * 0.125f : -3.0e38f;
        }
      }
    } else {
#pragma unroll
      for (int mf = 0; mf < 4; ++mf)
#pragma unroll
        for (int nf = 0; nf < 2; ++nf)
#pragma unroll
          for (int r = 0; r < 4; ++r) s[mf][nf][r] *= 0.125f;
    }

    // ---- online softmax (per q = column): local 16 + shfl 16,32 ----
#pragma unroll
    for (int nf = 0; nf < 2; ++nf) {
      float mx = -3.0e38f;
#pragma unroll
      for (int mf = 0; mf < 4; ++mf)
#pragma unroll
        for (int r = 0; r < 4; ++r) mx = fmaxf(mx, s[mf][nf][r]);
      mx = fmaxf(mx, __shfl_xor(mx, 16, 64));
      mx = fmaxf(mx, __shfl_xor(mx, 32, 64));
      const float m_new = fmaxf(m_r[nf], mx);
      const float al = __expf(m_r[nf] - m_new);
      m_r[nf] = m_new;
      float ps = 0.f;
#pragma unroll
      for (int mf = 0; mf < 4; ++mf) {
        u16x4 pk;
#pragma unroll
        for (int r = 0; r < 4; ++r) {
          const float e = __expf(s[mf][nf][r] - m_new);
          ps += e;
          pk[r] = f2bf(e);
        }
        *(u16x4*)&p_lds[wave][nf * 16 + c16][mf * 16 + quad * 4] = pk;
      }
      ps += __shfl_xor(ps, 16, 64);
      ps += __shfl_xor(ps, 32, 64);
      l_r[nf] = l_r[nf] * al + ps;
      if (quad == 0) alpha_lds[wave][nf * 16 + c16] = al;
    }
    __threadfence_block();  // drain this wave's LDS writes (p, alpha)

    // ---- rescale O (alpha indexed by row q in C-layout) ----
#pragma unroll
    for (int nf = 0; nf < 2; ++nf) {
      float alr[4];
#pragma unroll
      for (int r = 0; r < 4; ++r)
        alr[r] = alpha_lds[wave][nf * 16 + quad * 4 + r];
#pragma unroll
      for (int j = 0; j < 4; ++j)
#pragma unroll
        for (int r = 0; r < 4; ++r) o[nf][j][r] *= alr[r];
    }

    // ---- O += P @ V : D[m=q][n=d], A=P-frag, B=Vt-frag ----
    bf16x8 pf[2][2];
#pragma unroll
    for (int nf = 0; nf < 2; ++nf) {
      const unsigned short* pw = &p_lds[wave][nf * 16 + c16][quad * 8];
      pf[nf][0] = ld8_lds(pw);
      pf[nf][1] = ld8_lds(pw + 32);
    }
    __builtin_amdgcn_s_setprio(1);
#pragma unroll
    for (int j = 0; j < 4; ++j) {
      const unsigned short* vr = &vt_lds[bi][j * 16 + c16][quad * 8];
      const bf16x8 v0 = ld8_lds(vr);
      const bf16x8 v1 = ld8_lds(vr + 32);
#pragma unroll
      for (int nf = 0; nf < 2; ++nf) {
        o[nf][j] = __builtin_amdgcn_mfma_f32_16x16x32_bf16(pf[nf][0], v0,
                                                           o[nf][j], 0, 0, 0);
        o[nf][j] = __builtin_amdgcn_mfma_f32_16x16x32_bf16(pf[nf][1], v1,
                                                           o[nf][j], 0, 0, 0);
      }
    }
    __builtin_amdgcn_s_setprio(0);
  };

  // prologue: stage tile 0 into buf 0
  {
    u16x8 ka = *(const u16x8*)kp0;
    u16x8 kc = *(const u16x8*)(kp0 + 8);
    u16x8 va = *(const u16x8*)vp0;
    u16x8 vc = *(const u16x8*)(vp0 + 8);
    *(u16x4*)&k_lds[0][srow][scol]       = lo4(ka);
    *(u16x4*)&k_lds[0][srow][scol + 4]   = hi4(ka);
    *(u16x4*)&k_lds[0][srow][scol + 8]   = lo4(kc);
    *(u16x4*)&k_lds[0][srow][scol + 12]  = hi4(kc);
    *(u16x4*)&vt_lds[0][srow][scol]      = lo4(va);
    *(u16x4*)&vt_lds[0][srow][scol + 4]  = hi4(va);
    *(u16x4*)&vt_lds[0][srow][scol + 8]  = lo4(vc);
    *(u16x4*)&vt_lds[0][srow][scol + 12] = hi4(vc);
  }
  __syncthreads();

  int cur = 0;
  for (int t = 0; t < ntiles; ++t) {
    const int kb0 = t * 64;
    const bool pf = (t + 1 < ntiles);
    u16x8 ka, kc, va, vc;
    if (pf) {  // issue next-tile loads; consumed by ds_write after compute
      const unsigned short* kp = kp0 + (size_t)(kb0 + 64) * DM;
      ka = *(const u16x8*)kp;
      kc = *(const u16x8*)(kp + 8);
      const unsigned short* vp = vp0 + (kb0 + 64);
      va = *(const u16x8*)vp;
      vc = *(const u16x8*)(vp + 8);
    }
    if (t < ntA_w) subtile(qfA, oA, mA, lA, q_loA, kb0, cur);
    if (t < ntB_w) subtile(qfB, oB, mB, lB, q_loB, kb0, cur);
    if (pf) {
      const int nb = cur ^ 1;
      *(u16x4*)&k_lds[nb][srow][scol]       = lo4(ka);
      *(u16x4*)&k_lds[nb][srow][scol + 4]   = hi4(ka);
      *(u16x4*)&k_lds[nb][srow][scol + 8]   = lo4(kc);
      *(u16x4*)&k_lds[nb][srow][scol + 12]  = hi4(kc);
      *(u16x4*)&vt_lds[nb][srow][scol]      = lo4(va);
      *(u16x4*)&vt_lds[nb][srow][scol + 4]  = hi4(va);
      *(u16x4*)&vt_lds[nb][srow][scol + 8]  = lo4(vc);
      *(u16x4*)&vt_lds[nb][srow][scol + 12] = hi4(vc);
      __syncthreads();
      cur = nb;
    }
  }

  // ---- epilogue: O/l, C-layout scatter (q = row), A then B ----
  auto epi = [&](f32x4 (&o)[2][4], float (&l_r)[2], const int q_lo) {
    if (quad == 0) {
      l_lds[wave][c16] = l_r[0];
      l_lds[wave][16 + c16] = l_r[1];
    }
    __threadfence_block();
#pragma unroll
    for (int nf = 0; nf < 2; ++nf)
#pragma unroll
      for (int r = 0; r < 4; ++r) {
        const int qg = q_lo + nf * 16 + quad * 4 + r;
        const float inv = 1.0f / l_lds[wave][nf * 16 + quad * 4 + r];
        unsigned short* orow = Ow + rkbase + (size_t)qg * DM;
#pragma unroll
        for (int j = 0; j < 4; ++j)
          orow[j * 16 + c16] = f2bf(o[nf][j][r] * inv);
      }
  };
  epi(oA, lA, q_loA);
  __threadfence_block();
  epi(oB, lB, q_loB);
}

extern "C" void kernel_launch(void* const* d_in, const int* in_sizes, int n_in,
                              void* d_out, int out_size, void* d_ws, size_t ws_size,
                              hipStream_t stream) {
  const float* x_q  = (const float*)d_in[0];
  const float* x_kv = (const float*)d_in[1];
  const float* Wq   = (const float*)d_in[2];
  const float* Wk   = (const float*)d_in[3];
  const float* Wv   = (const float*)d_in[4];
  const float* Wo   = (const float*)d_in[5];
  float* out = (float*)d_out;

  // d_out doubles as early scratch; final GEMM reads only from ws.
  unsigned short* scr  = (unsigned short*)d_out;
  unsigned short* Sx   = scr;                          // x bf16 slot
  unsigned short* Wk_b = scr + (size_t)MROWS * DM;     // Wk|Wv|Wq contiguous
  unsigned short* Wv_b = Wk_b + (size_t)DM * DM;
  unsigned short* Wq_b = Wv_b + (size_t)DM * DM;

  unsigned short* qb   = (unsigned short*)d_ws;
  unsigned short* kb   = qb + (size_t)MROWS * DM;
  unsigned short* vtb  = kb + (size_t)MROWS * DM;      // Vt[b][h][d][t]
  unsigned short* Wo_b = vtb + (size_t)MROWS * DM;

  const int nW8 = DM * DM / 8;
  const int nX8 = MROWS * DM / 8;

  conv_w4<<<dim3(nW8 / 256, 4), 256, 0, stream>>>(Wk, Wv, Wq, Wo, Wk_b, Wo_b,
                                                  nW8);
  conv_f32_bf16<<<nX8 / 256, 256, 0, stream>>>(x_kv, Sx, nX8);

  // Fused K+V projection: B = [Wk_b ; Wv_b] (contiguous), N = 2048,
  // 1024 blocks = 4/CU.
  gemm128<3><<<dim3(2 * DM / 128, MROWS / 128), 256, 0, stream>>>(
      Sx, Wk_b, kb, vtb, MROWS, 2 * DM, DM);
  conv_f32_bf16<<<nX8 / 256, 256, 0, stream>>>(x_q, Sx, nX8);
  gemm128<0><<<dim3(DM / 128, MROWS / 128), 256, 0, stream>>>(
      Sx, Wq_b, qb, nullptr, MROWS, DM, DM);
  attn_flash2<<<dim3(8, NH, BB), 256, 0, stream>>>(qb, kb, vtb, qb);
  gemm128<1><<<dim3(DM / 128, MROWS / 128), 256, 0, stream>>>(
      qb, Wo_b, out, nullptr, MROWS, DM, DM);
}

// Round 6
// 295.789 us; speedup vs baseline: 1.1057x; 1.0241x over previous
//
#include <hip/hip_runtime.h>
#include <stdint.h>

#define T_SEQ 2048
#define NH 16
#define HD 64
#define DM 1024
#define BB 4
#define MROWS (BB * T_SEQ)   // 8192

typedef __attribute__((ext_vector_type(8))) __bf16 bf16x8;
typedef __attribute__((ext_vector_type(8))) unsigned short u16x8;
typedef __attribute__((ext_vector_type(4))) unsigned short u16x4;
typedef __attribute__((ext_vector_type(4))) float f32x4;

// Native cast -> compiler emits v_cvt_pk_bf16_f32 (RNE, pairs fuse).
__device__ __forceinline__ unsigned short f2bf(float f) {
  return __builtin_bit_cast(unsigned short, (__bf16)f);
}

__device__ __forceinline__ bf16x8 ld8_f32(const float* __restrict__ p) {
  f32x4 a = *(const f32x4*)p;
  f32x4 b = *(const f32x4*)(p + 4);
  u16x8 u;
#pragma unroll
  for (int i = 0; i < 4; ++i) {
    u[i]     = f2bf(a[i]);
    u[i + 4] = f2bf(b[i]);
  }
  return __builtin_bit_cast(bf16x8, u);
}

__device__ __forceinline__ bf16x8 ld8_bf(const unsigned short* p) {
  return __builtin_bit_cast(bf16x8, *(const u16x8*)p);
}

// 8-aligned LDS read as two b64s (stride-68 layouts are not 16B-aligned)
__device__ __forceinline__ bf16x8 ld8_lds(const unsigned short* p) {
  u16x4 a = *(const u16x4*)p;
  u16x4 b = *(const u16x4*)(p + 4);
  return __builtin_bit_cast(bf16x8,
      __builtin_shufflevector(a, b, 0, 1, 2, 3, 4, 5, 6, 7));
}

__device__ __forceinline__ u16x4 lo4(u16x8 v) {
  return __builtin_shufflevector(v, v, 0, 1, 2, 3);
}
__device__ __forceinline__ u16x4 hi4(u16x8 v) {
  return __builtin_shufflevector(v, v, 4, 5, 6, 7);
}

__device__ __forceinline__ void gload_lds16(const unsigned short* g,
                                            unsigned short* l) {
  __builtin_amdgcn_global_load_lds(
      (const __attribute__((address_space(1))) unsigned int*)g,
      (__attribute__((address_space(3))) unsigned int*)l, 16, 0, 0);
}

// ---------------------------------------------------------------------------
// fp32 -> bf16 elementwise (8 elems/thread).
// ---------------------------------------------------------------------------
__global__ __launch_bounds__(256) void conv_f32_bf16(
    const float* __restrict__ src, unsigned short* __restrict__ dst, int n8) {
  const int i = blockIdx.x * 256 + threadIdx.x;
  if (i < n8)
    *(u16x8*)(dst + (size_t)i * 8) =
        __builtin_bit_cast(u16x8, ld8_f32(src + (size_t)i * 8));
}

// Fused 4-weight conversion: y selects (src,dst). Wk_b/Wv_b/Wq_b contiguous.
__global__ __launch_bounds__(256) void conv_w4(
    const float* __restrict__ s0, const float* __restrict__ s1,
    const float* __restrict__ s2, const float* __restrict__ s3,
    unsigned short* __restrict__ d012, unsigned short* __restrict__ d3,
    int n8) {
  const int y = blockIdx.y;
  const float* src = (y == 0) ? s0 : (y == 1) ? s1 : (y == 2) ? s2 : s3;
  unsigned short* dst = (y < 3) ? d012 + (size_t)y * DM * DM : d3;
  const int i = blockIdx.x * 256 + threadIdx.x;
  if (i < n8)
    *(u16x8*)(dst + (size_t)i * 8) =
        __builtin_bit_cast(u16x8, ld8_f32(src + (size_t)i * 8));
}

// ---------------------------------------------------------------------------
// bf16 GEMM: C = A[M,K] @ B[N,K]^T. 128x128 tile, BK=64 (two BK=32 planes).
//
// R6: 2-PHASE DOUBLE-BUFFERED STAGING (T3 minimal recipe, m248/m230 ~680 TF
// for this tile). Old loop was barrier -> 8 gload_lds -> barrier(vmcnt0
// drain): full load latency exposed every K-step (R5 showed extra resident
// blocks don't fix it -> stall is intra-block). New loop issues tile t+1's
// gload_lds BEFORE computing tile t from the other buffer; the single
// end-of-iter __syncthreads (vmcnt0+lgkm0 drain) lands after ~350cy of
// ds_read+MFMA, so load latency hides under compute. LDS 64KB -> 2
// blocks/CU (grid already caps at 2/CU for N=1024).
// XCD remap: XCD owns contiguous m-panels (runtime nx). MODE 0: bf16
// row-major. MODE 1: f32 row-major. MODE 2: Vt[b][h][d][t]. MODE 3: fused
// K+V (N=2048): n0<DM -> K layout; else Vt layout (block-uniform branch).
// ---------------------------------------------------------------------------
template <int MODE>
__global__ __launch_bounds__(256) void gemm128(
    const unsigned short* __restrict__ A, const unsigned short* __restrict__ B,
    void* __restrict__ Cv, void* __restrict__ Cv2, int M, int N, int K) {
  __shared__ __align__(16) unsigned short As[2][2][128 * 32];
  __shared__ __align__(16) unsigned short Bs[2][2][128 * 32];

  const int t = threadIdx.x;
  const int lane = t & 63, wave = t >> 6;
  const int lin = (int)(blockIdx.x + gridDim.x * blockIdx.y);
  const int nx = N >> 7;                       // n-tiles
  const int mpx = (M >> 7) >> 3;               // m-panels per XCD
  const int xcd = lin & 7, slot = lin >> 3;
  const int m0 = (xcd * mpx + slot / nx) * 128;
  const int n0 = (slot % nx) * 128;

  const int srow = t >> 2;
  const int scol = (t & 3) * 8;
  const unsigned short* ga0 = A + (size_t)(m0 + srow) * K + scol;
  const unsigned short* ga1 = A + (size_t)(m0 + 64 + srow) * K + scol;
  const unsigned short* gb0 = B + (size_t)(n0 + srow) * K + scol;
  const unsigned short* gb1 = B + (size_t)(n0 + 64 + srow) * K + scol;
  const int lo0 = (wave * 16) * 32, lo1 = (64 + wave * 16) * 32;

  const int mw = (wave >> 1) * 64, nw = (wave & 1) * 64;
  const int fr = lane & 15, fq = (lane >> 4) * 8;

  f32x4 acc[4][4];
#pragma unroll
  for (int i = 0; i < 4; ++i)
#pragma unroll
    for (int j = 0; j < 4; ++j) acc[i][j] = (f32x4){0.f, 0.f, 0.f, 0.f};

  auto stage = [&](int buf, int k0) {
    gload_lds16(ga0 + k0,      &As[buf][0][lo0]);
    gload_lds16(ga1 + k0,      &As[buf][0][lo1]);
    gload_lds16(gb0 + k0,      &Bs[buf][0][lo0]);
    gload_lds16(gb1 + k0,      &Bs[buf][0][lo1]);
    gload_lds16(ga0 + k0 + 32, &As[buf][1][lo0]);
    gload_lds16(ga1 + k0 + 32, &As[buf][1][lo1]);
    gload_lds16(gb0 + k0 + 32, &Bs[buf][1][lo0]);
    gload_lds16(gb1 + k0 + 32, &Bs[buf][1][lo1]);
  };

  // prologue: stage tile 0 (latency exposed once)
  stage(0, 0);
  __syncthreads();

  const int NT = K >> 6;   // 16
  int cur = 0;
  for (int kt = 0; kt < NT; ++kt) {
    if (kt + 1 < NT) stage(cur ^ 1, (kt + 1) << 6);  // overlaps compute below
#pragma unroll
    for (int ks = 0; ks < 2; ++ks) {
      bf16x8 af[4], bfr[4];
#pragma unroll
      for (int i = 0; i < 4; ++i)
        af[i] = ld8_bf(&As[cur][ks][(mw + i * 16 + fr) * 32 + fq]);
#pragma unroll
      for (int j = 0; j < 4; ++j)
        bfr[j] = ld8_bf(&Bs[cur][ks][(nw + j * 16 + fr) * 32 + fq]);
#pragma unroll
      for (int i = 0; i < 4; ++i)
#pragma unroll
        for (int j = 0; j < 4; ++j)
          acc[i][j] = __builtin_amdgcn_mfma_f32_16x16x32_bf16(
              af[i], bfr[j], acc[i][j], 0, 0, 0);
    }
    __syncthreads();  // drains vmcnt(0): next buf ready; cur safe to overwrite
    cur ^= 1;
  }

  const int orow = (lane >> 4) * 4, ocol = lane & 15;
  const bool kv_lo = (MODE == 3) && (n0 < DM);  // block-uniform
#pragma unroll
  for (int i = 0; i < 4; ++i)
#pragma unroll
    for (int j = 0; j < 4; ++j) {
      if constexpr (MODE == 2) {
        // transposed pack: m -> (b,t), n -> (h,d); 4 r values = consecutive t
        const int mb = m0 + mw + i * 16 + orow;
        const int n = n0 + nw + j * 16 + ocol;
        u16x4 pk;
#pragma unroll
        for (int r = 0; r < 4; ++r) pk[r] = f2bf(acc[i][j][r]);
        unsigned short* dst = (unsigned short*)Cv +
            ((size_t)((mb >> 11) * NH + (n >> 6)) * HD + (n & 63)) * T_SEQ +
            (mb & 2047);
        *(u16x4*)dst = pk;
      } else if constexpr (MODE == 3) {
        const int mb = m0 + mw + i * 16 + orow;
        const int n = n0 + nw + j * 16 + ocol;
        if (kv_lo) {  // K path: bf16 row-major, stride DM
#pragma unroll
          for (int r = 0; r < 4; ++r)
            ((unsigned short*)Cv)[(size_t)(mb + r) * DM + n] =
                f2bf(acc[i][j][r]);
        } else {      // V path: Vt[b][h][d][t]
          const int nv = n - DM;
          u16x4 pk;
#pragma unroll
          for (int r = 0; r < 4; ++r) pk[r] = f2bf(acc[i][j][r]);
          unsigned short* dst = (unsigned short*)Cv2 +
              ((size_t)((mb >> 11) * NH + (nv >> 6)) * HD + (nv & 63)) *
                  T_SEQ +
              (mb & 2047);
          *(u16x4*)dst = pk;
        }
      } else {
#pragma unroll
        for (int r = 0; r < 4; ++r) {
          const size_t idx = (size_t)(m0 + mw + i * 16 + orow + r) * N +
                             (n0 + nw + j * 16 + ocol);
          if constexpr (MODE == 1)
            ((float*)Cv)[idx] = acc[i][j][r];
          else
            ((unsigned short*)Cv)[idx] = f2bf(acc[i][j][r]);
        }
      }
    }
}

// ---------------------------------------------------------------------------
// MFMA flash attention v2 (causal). R3/R5 structure (best measured: 88 µs).
// Paired q-tiles {15-pi, pi} per block for uniform work. S^T = K @ Q^T;
// V pre-transposed (Vt[b][h][d][t]). LDS stride 68 u16. K/V double-buffered,
// 1 barrier/tile. launch_bounds(256,2) = 256-VGPR budget (R1: spill trap).
// ---------------------------------------------------------------------------
#define ASTR 68

__global__ __launch_bounds__(256, 2) void attn_flash2(
    const unsigned short* Qw, const unsigned short* __restrict__ Kw,
    const unsigned short* __restrict__ Vt, unsigned short* Ow) {
  __shared__ __align__(16) unsigned short k_lds[2][64][ASTR];
  __shared__ __align__(16) unsigned short vt_lds[2][64][ASTR];
  __shared__ __align__(16) unsigned short p_lds[4][32][ASTR];
  __shared__ float alpha_lds[4][32];
  __shared__ float l_lds[4][32];

  const int tid = threadIdx.x, lane = tid & 63, wave = tid >> 6;
  const int c16 = lane & 15, quad = lane >> 4;
  const int b = blockIdx.z, h = blockIdx.y;
  const int pi = blockIdx.x;            // pair index 0..7
  const int qb0A = (15 - pi) * 128;     // heavy
  const int qb0B = pi * 128;            // light
  const size_t rkbase = (size_t)b * T_SEQ * DM + (size_t)h * HD;
  const size_t vtbase = (size_t)(b * NH + h) * HD * T_SEQ;

  const int q_loA = qb0A + wave * 32;
  const int q_loB = qb0B + wave * 32;

  // Q B-frags (resident): B[n=q][k=d], d = quad*8 + kf*32
  bf16x8 qfA[2][2], qfB[2][2];
#pragma unroll
  for (int nf = 0; nf < 2; ++nf) {
    const unsigned short* qpA =
        Qw + rkbase + (size_t)(q_loA + nf * 16 + c16) * DM + quad * 8;
    qfA[nf][0] = ld8_bf(qpA);
    qfA[nf][1] = ld8_bf(qpA + 32);
    const unsigned short* qpB =
        Qw + rkbase + (size_t)(q_loB + nf * 16 + c16) * DM + quad * 8;
    qfB[nf][0] = ld8_bf(qpB);
    qfB[nf][1] = ld8_bf(qpB + 32);
  }

  f32x4 oA[2][4], oB[2][4];
#pragma unroll
  for (int nf = 0; nf < 2; ++nf)
#pragma unroll
    for (int j = 0; j < 4; ++j) {
      oA[nf][j] = (f32x4){0.f, 0.f, 0.f, 0.f};
      oB[nf][j] = (f32x4){0.f, 0.f, 0.f, 0.f};
    }
  float mA[2] = {-3.0e38f, -3.0e38f}, lA[2] = {0.f, 0.f};
  float mB[2] = {-3.0e38f, -3.0e38f}, lB[2] = {0.f, 0.f};

  const int srow = tid >> 2;          // 0..63 (key idx for K, d idx for Vt)
  const int scol = (tid & 3) * 16;    // 0/16/32/48
  const int ntiles = (qb0A + 191) >> 6;     // heavy bound covers light
  const int ntA_w = (q_loA + 95) >> 6;
  const int ntB_w = (q_loB + 95) >> 6;

  const unsigned short* kp0 = Kw + rkbase + (size_t)srow * DM + scol;
  const unsigned short* vp0 = Vt + vtbase + (size_t)srow * T_SEQ + scol;

  // per-subtile compute: S^T -> online softmax -> rescale -> PV
  auto subtile = [&](const bf16x8 (&qf)[2][2], f32x4 (&o)[2][4],
                     float (&m_r)[2], float (&l_r)[2], const int q_lo,
                     const int kb0, const int bi) {
    // ---- S^T = K @ Q^T : D[m=key][n=q] ----
    f32x4 s[4][2];
    __builtin_amdgcn_s_setprio(1);
#pragma unroll
    for (int mf = 0; mf < 4; ++mf) {
      const unsigned short* kr = &k_lds[bi][mf * 16 + c16][quad * 8];
      const bf16x8 k0 = ld8_lds(kr);
      const bf16x8 k1 = ld8_lds(kr + 32);
#pragma unroll
      for (int nf = 0; nf < 2; ++nf) {
        f32x4 a = {0.f, 0.f, 0.f, 0.f};
        a = __builtin_amdgcn_mfma_f32_16x16x32_bf16(k0, qf[nf][0], a, 0, 0, 0);
        a = __builtin_amdgcn_mfma_f32_16x16x32_bf16(k1, qf[nf][1], a, 0, 0, 0);
        s[mf][nf] = a;
      }
    }
    __builtin_amdgcn_s_setprio(0);
    // scale + causal mask: key = kb0+mf*16+quad*4+r, q = q_lo+nf*16+c16
    if (kb0 + 63 > q_lo) {
#pragma unroll
      for (int mf = 0; mf < 4; ++mf) {
        const int key0 = kb0 + mf * 16 + quad * 4;
#pragma unroll
        for (int nf = 0; nf < 2; ++nf) {
          const int qg = q_lo + nf * 16 + c16;
#pragma unroll
          for (int r = 0; r < 4; ++r)
            s[mf][nf][r] =
                (key0 + r <= qg) ? s[mf][nf][r] * 0.125f : -3.0e38f;
        }
      }
    } else {
#pragma unroll
      for (int mf = 0; mf < 4; ++mf)
#pragma unroll
        for (int nf = 0; nf < 2; ++nf)
#pragma unroll
          for (int r = 0; r < 4; ++r) s[mf][nf][r] *= 0.125f;
    }

    // ---- online softmax (per q = column): local 16 + shfl 16,32 ----
#pragma unroll
    for (int nf = 0; nf < 2; ++nf) {
      float mx = -3.0e38f;
#pragma unroll
      for (int mf = 0; mf < 4; ++mf)
#pragma unroll
        for (int r = 0; r < 4; ++r) mx = fmaxf(mx, s[mf][nf][r]);
      mx = fmaxf(mx, __shfl_xor(mx, 16, 64));
      mx = fmaxf(mx, __shfl_xor(mx, 32, 64));
      const float m_new = fmaxf(m_r[nf], mx);
      const float al = __expf(m_r[nf] - m_new);
      m_r[nf] = m_new;
      float ps = 0.f;
#pragma unroll
      for (int mf = 0; mf < 4; ++mf) {
        u16x4 pk;
#pragma unroll
        for (int r = 0; r < 4; ++r) {
          const float e = __expf(s[mf][nf][r] - m_new);
          ps += e;
          pk[r] = f2bf(e);
        }
        *(u16x4*)&p_lds[wave][nf * 16 + c16][mf * 16 + quad * 4] = pk;
      }
      ps += __shfl_xor(ps, 16, 64);
      ps += __shfl_xor(ps, 32, 64);
      l_r[nf] = l_r[nf] * al + ps;
      if (quad == 0) alpha_lds[wave][nf * 16 + c16] = al;
    }
    __threadfence_block();  // drain this wave's LDS writes (p, alpha)

    // ---- rescale O (alpha indexed by row q in C-layout) ----
#pragma unroll
    for (int nf = 0; nf < 2; ++nf) {
      float alr[4];
#pragma unroll
      for (int r = 0; r < 4; ++r)
        alr[r] = alpha_lds[wave][nf * 16 + quad * 4 + r];
#pragma unroll
      for (int j = 0; j < 4; ++j)
#pragma unroll
        for (int r = 0; r < 4; ++r) o[nf][j][r] *= alr[r];
    }

    // ---- O += P @ V : D[m=q][n=d], A=P-frag, B=Vt-frag ----
    bf16x8 pf[2][2];
#pragma unroll
    for (int nf = 0; nf < 2; ++nf) {
      const unsigned short* pw = &p_lds[wave][nf * 16 + c16][quad * 8];
      pf[nf][0] = ld8_lds(pw);
      pf[nf][1] = ld8_lds(pw + 32);
    }
    __builtin_amdgcn_s_setprio(1);
#pragma unroll
    for (int j = 0; j < 4; ++j) {
      const unsigned short* vr = &vt_lds[bi][j * 16 + c16][quad * 8];
      const bf16x8 v0 = ld8_lds(vr);
      const bf16x8 v1 = ld8_lds(vr + 32);
#pragma unroll
      for (int nf = 0; nf < 2; ++nf) {
        o[nf][j] = __builtin_amdgcn_mfma_f32_16x16x32_bf16(pf[nf][0], v0,
                                                           o[nf][j], 0, 0, 0);
        o[nf][j] = __builtin_amdgcn_mfma_f32_16x16x32_bf16(pf[nf][1], v1,
                                                           o[nf][j], 0, 0, 0);
      }
    }
    __builtin_amdgcn_s_setprio(0);
  };

  // prologue: stage tile 0 into buf 0
  {
    u16x8 ka = *(const u16x8*)kp0;
    u16x8 kc = *(const u16x8*)(kp0 + 8);
    u16x8 va = *(const u16x8*)vp0;
    u16x8 vc = *(const u16x8*)(vp0 + 8);
    *(u16x4*)&k_lds[0][srow][scol]       = lo4(ka);
    *(u16x4*)&k_lds[0][srow][scol + 4]   = hi4(ka);
    *(u16x4*)&k_lds[0][srow][scol + 8]   = lo4(kc);
    *(u16x4*)&k_lds[0][srow][scol + 12]  = hi4(kc);
    *(u16x4*)&vt_lds[0][srow][scol]      = lo4(va);
    *(u16x4*)&vt_lds[0][srow][scol + 4]  = hi4(va);
    *(u16x4*)&vt_lds[0][srow][scol + 8]  = lo4(vc);
    *(u16x4*)&vt_lds[0][srow][scol + 12] = hi4(vc);
  }
  __syncthreads();

  int cur = 0;
  for (int t = 0; t < ntiles; ++t) {
    const int kb0 = t * 64;
    const bool pf = (t + 1 < ntiles);
    u16x8 ka, kc, va, vc;
    if (pf) {  // issue next-tile loads; consumed by ds_write after compute
      const unsigned short* kp = kp0 + (size_t)(kb0 + 64) * DM;
      ka = *(const u16x8*)kp;
      kc = *(const u16x8*)(kp + 8);
      const unsigned short* vp = vp0 + (kb0 + 64);
      va = *(const u16x8*)vp;
      vc = *(const u16x8*)(vp + 8);
    }
    if (t < ntA_w) subtile(qfA, oA, mA, lA, q_loA, kb0, cur);
    if (t < ntB_w) subtile(qfB, oB, mB, lB, q_loB, kb0, cur);
    if (pf) {
      const int nb = cur ^ 1;
      *(u16x4*)&k_lds[nb][srow][scol]       = lo4(ka);
      *(u16x4*)&k_lds[nb][srow][scol + 4]   = hi4(ka);
      *(u16x4*)&k_lds[nb][srow][scol + 8]   = lo4(kc);
      *(u16x4*)&k_lds[nb][srow][scol + 12]  = hi4(kc);
      *(u16x4*)&vt_lds[nb][srow][scol]      = lo4(va);
      *(u16x4*)&vt_lds[nb][srow][scol + 4]  = hi4(va);
      *(u16x4*)&vt_lds[nb][srow][scol + 8]  = lo4(vc);
      *(u16x4*)&vt_lds[nb][srow][scol + 12] = hi4(vc);
      __syncthreads();
      cur = nb;
    }
  }

  // ---- epilogue: O/l, C-layout scatter (q = row), A then B ----
  auto epi = [&](f32x4 (&o)[2][4], float (&l_r)[2], const int q_lo) {
    if (quad == 0) {
      l_lds[wave][c16] = l_r[0];
      l_lds[wave][16 + c16] = l_r[1];
    }
    __threadfence_block();
#pragma unroll
    for (int nf = 0; nf < 2; ++nf)
#pragma unroll
      for (int r = 0; r < 4; ++r) {
        const int qg = q_lo + nf * 16 + quad * 4 + r;
        const float inv = 1.0f / l_lds[wave][nf * 16 + quad * 4 + r];
        unsigned short* orow = Ow + rkbase + (size_t)qg * DM;
#pragma unroll
        for (int j = 0; j < 4; ++j)
          orow[j * 16 + c16] = f2bf(o[nf][j][r] * inv);
      }
  };
  epi(oA, lA, q_loA);
  __threadfence_block();
  epi(oB, lB, q_loB);
}

extern "C" void kernel_launch(void* const* d_in, const int* in_sizes, int n_in,
                              void* d_out, int out_size, void* d_ws, size_t ws_size,
                              hipStream_t stream) {
  const float* x_q  = (const float*)d_in[0];
  const float* x_kv = (const float*)d_in[1];
  const float* Wq   = (const float*)d_in[2];
  const float* Wk   = (const float*)d_in[3];
  const float* Wv   = (const float*)d_in[4];
  const float* Wo   = (const float*)d_in[5];
  float* out = (float*)d_out;

  // d_out doubles as early scratch; final GEMM reads only from ws.
  unsigned short* scr  = (unsigned short*)d_out;
  unsigned short* Sx   = scr;                          // x bf16 slot
  unsigned short* Wk_b = scr + (size_t)MROWS * DM;     // Wk|Wv|Wq contiguous
  unsigned short* Wv_b = Wk_b + (size_t)DM * DM;
  unsigned short* Wq_b = Wv_b + (size_t)DM * DM;

  unsigned short* qb   = (unsigned short*)d_ws;
  unsigned short* kb   = qb + (size_t)MROWS * DM;
  unsigned short* vtb  = kb + (size_t)MROWS * DM;      // Vt[b][h][d][t]
  unsigned short* Wo_b = vtb + (size_t)MROWS * DM;

  const int nW8 = DM * DM / 8;
  const int nX8 = MROWS * DM / 8;

  conv_w4<<<dim3(nW8 / 256, 4), 256, 0, stream>>>(Wk, Wv, Wq, Wo, Wk_b, Wo_b,
                                                  nW8);
  conv_f32_bf16<<<nX8 / 256, 256, 0, stream>>>(x_kv, Sx, nX8);

  // Fused K+V projection: B = [Wk_b ; Wv_b] (contiguous), N = 2048.
  gemm128<3><<<dim3(2 * DM / 128, MROWS / 128), 256, 0, stream>>>(
      Sx, Wk_b, kb, vtb, MROWS, 2 * DM, DM);
  conv_f32_bf16<<<nX8 / 256, 256, 0, stream>>>(x_q, Sx, nX8);
  gemm128<0><<<dim3(DM / 128, MROWS / 128), 256, 0, stream>>>(
      Sx, Wq_b, qb, nullptr, MROWS, DM, DM);
  attn_flash2<<<dim3(8, NH, BB), 256, 0, stream>>>(qb, kb, vtb, qb);
  gemm128<1><<<dim3(DM / 128, MROWS / 128), 256, 0, stream>>>(
      qb, Wo_b, out, nullptr, MROWS, DM, DM);
}

// Round 7
// 294.484 us; speedup vs baseline: 1.1106x; 1.0044x over previous
//
#include <hip/hip_runtime.h>
#include <stdint.h>

#define T_SEQ 2048
#define NH 16
#define HD 64
#define DM 1024
#define BB 4
#define MROWS (BB * T_SEQ)   // 8192

// Q projection is pre-scaled by 1/sqrt(HD) * log2(e) so attention scores are
// already in the log2 domain: P = exp2(s - m), alpha = exp2(m_old - m_new).
#define QSCALE 0.18033688011112042f  // 0.125 * log2(e)

typedef __attribute__((ext_vector_type(8))) __bf16 bf16x8;
typedef __attribute__((ext_vector_type(8))) unsigned short u16x8;
typedef __attribute__((ext_vector_type(4))) unsigned short u16x4;
typedef __attribute__((ext_vector_type(4))) float f32x4;

// Native cast -> compiler emits v_cvt_pk_bf16_f32 (RNE, pairs fuse).
__device__ __forceinline__ unsigned short f2bf(float f) {
  return __builtin_bit_cast(unsigned short, (__bf16)f);
}

__device__ __forceinline__ bf16x8 ld8_f32(const float* __restrict__ p) {
  f32x4 a = *(const f32x4*)p;
  f32x4 b = *(const f32x4*)(p + 4);
  u16x8 u;
#pragma unroll
  for (int i = 0; i < 4; ++i) {
    u[i]     = f2bf(a[i]);
    u[i + 4] = f2bf(b[i]);
  }
  return __builtin_bit_cast(bf16x8, u);
}

__device__ __forceinline__ bf16x8 ld8_bf(const unsigned short* p) {
  return __builtin_bit_cast(bf16x8, *(const u16x8*)p);
}

// 8-aligned LDS read as two b64s (stride-68 layouts are not 16B-aligned)
__device__ __forceinline__ bf16x8 ld8_lds(const unsigned short* p) {
  u16x4 a = *(const u16x4*)p;
  u16x4 b = *(const u16x4*)(p + 4);
  return __builtin_bit_cast(bf16x8,
      __builtin_shufflevector(a, b, 0, 1, 2, 3, 4, 5, 6, 7));
}

__device__ __forceinline__ u16x4 lo4(u16x8 v) {
  return __builtin_shufflevector(v, v, 0, 1, 2, 3);
}
__device__ __forceinline__ u16x4 hi4(u16x8 v) {
  return __builtin_shufflevector(v, v, 4, 5, 6, 7);
}

__device__ __forceinline__ void gload_lds16(const unsigned short* g,
                                            unsigned short* l) {
  __builtin_amdgcn_global_load_lds(
      (const __attribute__((address_space(1))) unsigned int*)g,
      (__attribute__((address_space(3))) unsigned int*)l, 16, 0, 0);
}

// ---------------------------------------------------------------------------
// fp32 -> bf16 elementwise (8 elems/thread).
// ---------------------------------------------------------------------------
__global__ __launch_bounds__(256) void conv_f32_bf16(
    const float* __restrict__ src, unsigned short* __restrict__ dst, int n8) {
  const int i = blockIdx.x * 256 + threadIdx.x;
  if (i < n8)
    *(u16x8*)(dst + (size_t)i * 8) =
        __builtin_bit_cast(u16x8, ld8_f32(src + (size_t)i * 8));
}

// R7: fused stage-1 conversion — 4 weights + x_kv in ONE dispatch (saves
// launch gaps). Segment select is block-uniform. All sizes are exact
// multiples of 2048 elements, so no bounds checks.
__global__ __launch_bounds__(256) void conv_stage1(
    const float* __restrict__ Wk, const float* __restrict__ Wv,
    const float* __restrict__ Wq, const float* __restrict__ Wo,
    const float* __restrict__ xkv, unsigned short* __restrict__ Wkb012,
    unsigned short* __restrict__ Wob, unsigned short* __restrict__ Sx) {
  const int bid = blockIdx.x;
  const int WSEG = (DM * DM / 8) / 256;  // 512 blocks per weight
  if (bid < 4 * WSEG) {
    const int w = bid >> 9;
    const float* src = (w == 0) ? Wk : (w == 1) ? Wv : (w == 2) ? Wq : Wo;
    unsigned short* dst = (w < 3) ? Wkb012 + (size_t)w * DM * DM : Wob;
    const int i = (bid & (WSEG - 1)) * 256 + threadIdx.x;
    *(u16x8*)(dst + (size_t)i * 8) =
        __builtin_bit_cast(u16x8, ld8_f32(src + (size_t)i * 8));
  } else {
    const int i = (bid - 4 * WSEG) * 256 + threadIdx.x;
    *(u16x8*)(Sx + (size_t)i * 8) =
        __builtin_bit_cast(u16x8, ld8_f32(xkv + (size_t)i * 8));
  }
}

// ---------------------------------------------------------------------------
// bf16 GEMM: C = A[M,K] @ B[N,K]^T. 128x128 tile, BK=64 (two BK=32 planes),
// 2-phase double-buffered gload_lds staging (R6). XCD remap: XCD owns
// contiguous m-panels. MODE 0: bf16 row-major. MODE 1: f32 row-major.
// MODE 2: Vt[b][h][d][t]. MODE 3: fused K+V (N=2048; n0<DM -> K layout,
// else Vt layout, block-uniform). MODE 4 (R7): bf16 row-major scaled by
// QSCALE (folds attn's 1/8 * log2e into the Q projection epilogue).
// ---------------------------------------------------------------------------
template <int MODE>
__global__ __launch_bounds__(256) void gemm128(
    const unsigned short* __restrict__ A, const unsigned short* __restrict__ B,
    void* __restrict__ Cv, void* __restrict__ Cv2, int M, int N, int K) {
  __shared__ __align__(16) unsigned short As[2][2][128 * 32];
  __shared__ __align__(16) unsigned short Bs[2][2][128 * 32];

  const int t = threadIdx.x;
  const int lane = t & 63, wave = t >> 6;
  const int lin = (int)(blockIdx.x + gridDim.x * blockIdx.y);
  const int nx = N >> 7;                       // n-tiles
  const int mpx = (M >> 7) >> 3;               // m-panels per XCD
  const int xcd = lin & 7, slot = lin >> 3;
  const int m0 = (xcd * mpx + slot / nx) * 128;
  const int n0 = (slot % nx) * 128;

  const int srow = t >> 2;
  const int scol = (t & 3) * 8;
  const unsigned short* ga0 = A + (size_t)(m0 + srow) * K + scol;
  const unsigned short* ga1 = A + (size_t)(m0 + 64 + srow) * K + scol;
  const unsigned short* gb0 = B + (size_t)(n0 + srow) * K + scol;
  const unsigned short* gb1 = B + (size_t)(n0 + 64 + srow) * K + scol;
  const int lo0 = (wave * 16) * 32, lo1 = (64 + wave * 16) * 32;

  const int mw = (wave >> 1) * 64, nw = (wave & 1) * 64;
  const int fr = lane & 15, fq = (lane >> 4) * 8;

  f32x4 acc[4][4];
#pragma unroll
  for (int i = 0; i < 4; ++i)
#pragma unroll
    for (int j = 0; j < 4; ++j) acc[i][j] = (f32x4){0.f, 0.f, 0.f, 0.f};

  auto stage = [&](int buf, int k0) {
    gload_lds16(ga0 + k0,      &As[buf][0][lo0]);
    gload_lds16(ga1 + k0,      &As[buf][0][lo1]);
    gload_lds16(gb0 + k0,      &Bs[buf][0][lo0]);
    gload_lds16(gb1 + k0,      &Bs[buf][0][lo1]);
    gload_lds16(ga0 + k0 + 32, &As[buf][1][lo0]);
    gload_lds16(ga1 + k0 + 32, &As[buf][1][lo1]);
    gload_lds16(gb0 + k0 + 32, &Bs[buf][1][lo0]);
    gload_lds16(gb1 + k0 + 32, &Bs[buf][1][lo1]);
  };

  // prologue: stage tile 0 (latency exposed once)
  stage(0, 0);
  __syncthreads();

  const int NT = K >> 6;   // 16
  int cur = 0;
  for (int kt = 0; kt < NT; ++kt) {
    if (kt + 1 < NT) stage(cur ^ 1, (kt + 1) << 6);  // overlaps compute below
#pragma unroll
    for (int ks = 0; ks < 2; ++ks) {
      bf16x8 af[4], bfr[4];
#pragma unroll
      for (int i = 0; i < 4; ++i)
        af[i] = ld8_bf(&As[cur][ks][(mw + i * 16 + fr) * 32 + fq]);
#pragma unroll
      for (int j = 0; j < 4; ++j)
        bfr[j] = ld8_bf(&Bs[cur][ks][(nw + j * 16 + fr) * 32 + fq]);
#pragma unroll
      for (int i = 0; i < 4; ++i)
#pragma unroll
        for (int j = 0; j < 4; ++j)
          acc[i][j] = __builtin_amdgcn_mfma_f32_16x16x32_bf16(
              af[i], bfr[j], acc[i][j], 0, 0, 0);
    }
    __syncthreads();  // drains vmcnt(0): next buf ready; cur safe to overwrite
    cur ^= 1;
  }

  const int orow = (lane >> 4) * 4, ocol = lane & 15;
  const bool kv_lo = (MODE == 3) && (n0 < DM);  // block-uniform
#pragma unroll
  for (int i = 0; i < 4; ++i)
#pragma unroll
    for (int j = 0; j < 4; ++j) {
      if constexpr (MODE == 2) {
        const int mb = m0 + mw + i * 16 + orow;
        const int n = n0 + nw + j * 16 + ocol;
        u16x4 pk;
#pragma unroll
        for (int r = 0; r < 4; ++r) pk[r] = f2bf(acc[i][j][r]);
        unsigned short* dst = (unsigned short*)Cv +
            ((size_t)((mb >> 11) * NH + (n >> 6)) * HD + (n & 63)) * T_SEQ +
            (mb & 2047);
        *(u16x4*)dst = pk;
      } else if constexpr (MODE == 3) {
        const int mb = m0 + mw + i * 16 + orow;
        const int n = n0 + nw + j * 16 + ocol;
        if (kv_lo) {  // K path: bf16 row-major, stride DM
#pragma unroll
          for (int r = 0; r < 4; ++r)
            ((unsigned short*)Cv)[(size_t)(mb + r) * DM + n] =
                f2bf(acc[i][j][r]);
        } else {      // V path: Vt[b][h][d][t]
          const int nv = n - DM;
          u16x4 pk;
#pragma unroll
          for (int r = 0; r < 4; ++r) pk[r] = f2bf(acc[i][j][r]);
          unsigned short* dst = (unsigned short*)Cv2 +
              ((size_t)((mb >> 11) * NH + (nv >> 6)) * HD + (nv & 63)) *
                  T_SEQ +
              (mb & 2047);
          *(u16x4*)dst = pk;
        }
      } else {
#pragma unroll
        for (int r = 0; r < 4; ++r) {
          const size_t idx = (size_t)(m0 + mw + i * 16 + orow + r) * N +
                             (n0 + nw + j * 16 + ocol);
          float v = acc[i][j][r];
          if constexpr (MODE == 4) v *= QSCALE;
          if constexpr (MODE == 1)
            ((float*)Cv)[idx] = v;
          else
            ((unsigned short*)Cv)[idx] = f2bf(v);
        }
      }
    }
}

// ---------------------------------------------------------------------------
// MFMA flash attention v2 (causal). Paired q-tiles {15-pi, pi} per block for
// uniform work. S^T = K @ Q^T; V pre-transposed (Vt[b][h][d][t]). LDS stride
// 68 u16. K/V double-buffered, 1 barrier/tile. launch_bounds(256,2) =
// 256-VGPR budget (R1: spill trap at tighter budgets).
//
// R7 VALU diet (attn was 3:1 VALU:MFMA): scores arrive pre-scaled in the
// log2 domain (QSCALE folded into Q projection) -> no per-element scale mul,
// masked branch is a pure select, exp is exp2f direct. alpha/l exchanged via
// width-16 shuffles (no LDS round-trip, no threadfence). Defer-max (T13,
// THR=8): skip O-rescale + m-update when __all(mx - m <= 8); P bounded by
// 2^8, exact normalization in epilogue.
// ---------------------------------------------------------------------------
#define ASTR 68

__global__ __launch_bounds__(256, 2) void attn_flash2(
    const unsigned short* Qw, const unsigned short* __restrict__ Kw,
    const unsigned short* __restrict__ Vt, unsigned short* Ow) {
  __shared__ __align__(16) unsigned short k_lds[2][64][ASTR];
  __shared__ __align__(16) unsigned short vt_lds[2][64][ASTR];
  __shared__ __align__(16) unsigned short p_lds[4][32][ASTR];

  const int tid = threadIdx.x, lane = tid & 63, wave = tid >> 6;
  const int c16 = lane & 15, quad = lane >> 4;
  const int b = blockIdx.z, h = blockIdx.y;
  const int pi = blockIdx.x;            // pair index 0..7
  const int qb0A = (15 - pi) * 128;     // heavy
  const int qb0B = pi * 128;            // light
  const size_t rkbase = (size_t)b * T_SEQ * DM + (size_t)h * HD;
  const size_t vtbase = (size_t)(b * NH + h) * HD * T_SEQ;

  const int q_loA = qb0A + wave * 32;
  const int q_loB = qb0B + wave * 32;

  // Q B-frags (resident): B[n=q][k=d], d = quad*8 + kf*32
  bf16x8 qfA[2][2], qfB[2][2];
#pragma unroll
  for (int nf = 0; nf < 2; ++nf) {
    const unsigned short* qpA =
        Qw + rkbase + (size_t)(q_loA + nf * 16 + c16) * DM + quad * 8;
    qfA[nf][0] = ld8_bf(qpA);
    qfA[nf][1] = ld8_bf(qpA + 32);
    const unsigned short* qpB =
        Qw + rkbase + (size_t)(q_loB + nf * 16 + c16) * DM + quad * 8;
    qfB[nf][0] = ld8_bf(qpB);
    qfB[nf][1] = ld8_bf(qpB + 32);
  }

  f32x4 oA[2][4], oB[2][4];
#pragma unroll
  for (int nf = 0; nf < 2; ++nf)
#pragma unroll
    for (int j = 0; j < 4; ++j) {
      oA[nf][j] = (f32x4){0.f, 0.f, 0.f, 0.f};
      oB[nf][j] = (f32x4){0.f, 0.f, 0.f, 0.f};
    }
  float mA[2] = {-3.0e38f, -3.0e38f}, lA[2] = {0.f, 0.f};
  float mB[2] = {-3.0e38f, -3.0e38f}, lB[2] = {0.f, 0.f};

  const int srow = tid >> 2;          // 0..63 (key idx for K, d idx for Vt)
  const int scol = (tid & 3) * 16;    // 0/16/32/48
  const int ntiles = (qb0A + 191) >> 6;     // heavy bound covers light
  const int ntA_w = (q_loA + 95) >> 6;
  const int ntB_w = (q_loB + 95) >> 6;

  const unsigned short* kp0 = Kw + rkbase + (size_t)srow * DM + scol;
  const unsigned short* vp0 = Vt + vtbase + (size_t)srow * T_SEQ + scol;

  // per-subtile compute: S^T -> online softmax -> PV
  auto subtile = [&](const bf16x8 (&qf)[2][2], f32x4 (&o)[2][4],
                     float (&m_r)[2], float (&l_r)[2], const int q_lo,
                     const int kb0, const int bi) {
    // ---- S^T = K @ Q^T : D[m=key][n=q] (scores already * QSCALE) ----
    f32x4 s[4][2];
    __builtin_amdgcn_s_setprio(1);
#pragma unroll
    for (int mf = 0; mf < 4; ++mf) {
      const unsigned short* kr = &k_lds[bi][mf * 16 + c16][quad * 8];
      const bf16x8 k0 = ld8_lds(kr);
      const bf16x8 k1 = ld8_lds(kr + 32);
#pragma unroll
      for (int nf = 0; nf < 2; ++nf) {
        f32x4 a = {0.f, 0.f, 0.f, 0.f};
        a = __builtin_amdgcn_mfma_f32_16x16x32_bf16(k0, qf[nf][0], a, 0, 0, 0);
        a = __builtin_amdgcn_mfma_f32_16x16x32_bf16(k1, qf[nf][1], a, 0, 0, 0);
        s[mf][nf] = a;
      }
    }
    __builtin_amdgcn_s_setprio(0);
    // causal mask: key = kb0+mf*16+quad*4+r, q = q_lo+nf*16+c16 (pure select)
    if (kb0 + 63 > q_lo) {
#pragma unroll
      for (int mf = 0; mf < 4; ++mf) {
        const int key0 = kb0 + mf * 16 + quad * 4;
#pragma unroll
        for (int nf = 0; nf < 2; ++nf) {
          const int qg = q_lo + nf * 16 + c16;
#pragma unroll
          for (int r = 0; r < 4; ++r)
            if (key0 + r > qg) s[mf][nf][r] = -3.0e38f;
        }
      }
    }

    // ---- online softmax (per q = column): local 16 + shfl 16,32 ----
#pragma unroll
    for (int nf = 0; nf < 2; ++nf) {
      float mx = -3.0e38f;
#pragma unroll
      for (int mf = 0; mf < 4; ++mf)
#pragma unroll
        for (int r = 0; r < 4; ++r) mx = fmaxf(mx, s[mf][nf][r]);
      mx = fmaxf(mx, __shfl_xor(mx, 16, 64));
      mx = fmaxf(mx, __shfl_xor(mx, 32, 64));
      // defer-max: if tile max is within THR of running max, keep m_r
      // (P bounded by 2^8) and skip the O-rescale entirely.
      if (!__all(mx - m_r[nf] <= 8.0f)) {
        const float m_new = fmaxf(m_r[nf], mx);
        const float al = exp2f(m_r[nf] - m_new);
        m_r[nf] = m_new;
        l_r[nf] *= al;
        float alr[4];
#pragma unroll
        for (int r = 0; r < 4; ++r) alr[r] = __shfl(al, quad * 4 + r, 16);
#pragma unroll
        for (int j = 0; j < 4; ++j)
#pragma unroll
          for (int r = 0; r < 4; ++r) o[nf][j][r] *= alr[r];
      }
      float ps = 0.f;
#pragma unroll
      for (int mf = 0; mf < 4; ++mf) {
        u16x4 pk;
#pragma unroll
        for (int r = 0; r < 4; ++r) {
          const float e = exp2f(s[mf][nf][r] - m_r[nf]);
          ps += e;
          pk[r] = f2bf(e);
        }
        *(u16x4*)&p_lds[wave][nf * 16 + c16][mf * 16 + quad * 4] = pk;
      }
      ps += __shfl_xor(ps, 16, 64);
      ps += __shfl_xor(ps, 32, 64);
      l_r[nf] += ps;
    }
    __threadfence_block();  // order this wave's p_lds writes before reads

    // ---- O += P @ V : D[m=q][n=d], A=P-frag, B=Vt-frag ----
    bf16x8 pf[2][2];
#pragma unroll
    for (int nf = 0; nf < 2; ++nf) {
      const unsigned short* pw = &p_lds[wave][nf * 16 + c16][quad * 8];
      pf[nf][0] = ld8_lds(pw);
      pf[nf][1] = ld8_lds(pw + 32);
    }
    __builtin_amdgcn_s_setprio(1);
#pragma unroll
    for (int j = 0; j < 4; ++j) {
      const unsigned short* vr = &vt_lds[bi][j * 16 + c16][quad * 8];
      const bf16x8 v0 = ld8_lds(vr);
      const bf16x8 v1 = ld8_lds(vr + 32);
#pragma unroll
      for (int nf = 0; nf < 2; ++nf) {
        o[nf][j] = __builtin_amdgcn_mfma_f32_16x16x32_bf16(pf[nf][0], v0,
                                                           o[nf][j], 0, 0, 0);
        o[nf][j] = __builtin_amdgcn_mfma_f32_16x16x32_bf16(pf[nf][1], v1,
                                                           o[nf][j], 0, 0, 0);
      }
    }
    __builtin_amdgcn_s_setprio(0);
  };

  // prologue: stage tile 0 into buf 0
  {
    u16x8 ka = *(const u16x8*)kp0;
    u16x8 kc = *(const u16x8*)(kp0 + 8);
    u16x8 va = *(const u16x8*)vp0;
    u16x8 vc = *(const u16x8*)(vp0 + 8);
    *(u16x4*)&k_lds[0][srow][scol]       = lo4(ka);
    *(u16x4*)&k_lds[0][srow][scol + 4]   = hi4(ka);
    *(u16x4*)&k_lds[0][srow][scol + 8]   = lo4(kc);
    *(u16x4*)&k_lds[0][srow][scol + 12]  = hi4(kc);
    *(u16x4*)&vt_lds[0][srow][scol]      = lo4(va);
    *(u16x4*)&vt_lds[0][srow][scol + 4]  = hi4(va);
    *(u16x4*)&vt_lds[0][srow][scol + 8]  = lo4(vc);
    *(u16x4*)&vt_lds[0][srow][scol + 12] = hi4(vc);
  }
  __syncthreads();

  int cur = 0;
  for (int t = 0; t < ntiles; ++t) {
    const int kb0 = t * 64;
    const bool pf = (t + 1 < ntiles);
    u16x8 ka, kc, va, vc;
    if (pf) {  // issue next-tile loads; consumed by ds_write after compute
      const unsigned short* kp = kp0 + (size_t)(kb0 + 64) * DM;
      ka = *(const u16x8*)kp;
      kc = *(const u16x8*)(kp + 8);
      const unsigned short* vp = vp0 + (kb0 + 64);
      va = *(const u16x8*)vp;
      vc = *(const u16x8*)(vp + 8);
    }
    if (t < ntA_w) subtile(qfA, oA, mA, lA, q_loA, kb0, cur);
    if (t < ntB_w) subtile(qfB, oB, mB, lB, q_loB, kb0, cur);
    if (pf) {
      const int nb = cur ^ 1;
      *(u16x4*)&k_lds[nb][srow][scol]       = lo4(ka);
      *(u16x4*)&k_lds[nb][srow][scol + 4]   = hi4(ka);
      *(u16x4*)&k_lds[nb][srow][scol + 8]   = lo4(kc);
      *(u16x4*)&k_lds[nb][srow][scol + 12]  = hi4(kc);
      *(u16x4*)&vt_lds[nb][srow][scol]      = lo4(va);
      *(u16x4*)&vt_lds[nb][srow][scol + 4]  = hi4(va);
      *(u16x4*)&vt_lds[nb][srow][scol + 8]  = lo4(vc);
      *(u16x4*)&vt_lds[nb][srow][scol + 12] = hi4(vc);
      __syncthreads();
      cur = nb;
    }
  }

  // ---- epilogue: O/l, C-layout scatter (q = row); l via width-16 shfl ----
  auto epi = [&](f32x4 (&o)[2][4], float (&l_r)[2], const int q_lo) {
#pragma unroll
    for (int nf = 0; nf < 2; ++nf)
#pragma unroll
      for (int r = 0; r < 4; ++r) {
        const int qg = q_lo + nf * 16 + quad * 4 + r;
        const float inv = 1.0f / __shfl(l_r[nf], quad * 4 + r, 16);
        unsigned short* orow = Ow + rkbase + (size_t)qg * DM;
#pragma unroll
        for (int j = 0; j < 4; ++j)
          orow[j * 16 + c16] = f2bf(o[nf][j][r] * inv);
      }
  };
  epi(oA, lA, q_loA);
  epi(oB, lB, q_loB);
}

extern "C" void kernel_launch(void* const* d_in, const int* in_sizes, int n_in,
                              void* d_out, int out_size, void* d_ws, size_t ws_size,
                              hipStream_t stream) {
  const float* x_q  = (const float*)d_in[0];
  const float* x_kv = (const float*)d_in[1];
  const float* Wq   = (const float*)d_in[2];
  const float* Wk   = (const float*)d_in[3];
  const float* Wv   = (const float*)d_in[4];
  const float* Wo   = (const float*)d_in[5];
  float* out = (float*)d_out;

  // d_out doubles as early scratch; final GEMM reads only from ws.
  unsigned short* scr  = (unsigned short*)d_out;
  unsigned short* Sx   = scr;                          // x bf16 slot
  unsigned short* Wk_b = scr + (size_t)MROWS * DM;     // Wk|Wv|Wq contiguous
  unsigned short* Wv_b = Wk_b + (size_t)DM * DM;
  unsigned short* Wq_b = Wv_b + (size_t)DM * DM;

  unsigned short* qb   = (unsigned short*)d_ws;
  unsigned short* kb   = qb + (size_t)MROWS * DM;
  unsigned short* vtb  = kb + (size_t)MROWS * DM;      // Vt[b][h][d][t]
  unsigned short* Wo_b = vtb + (size_t)MROWS * DM;

  const int nW8 = DM * DM / 8;
  const int nX8 = MROWS * DM / 8;
  (void)Wv_b;

  // stage 1: all 4 weights + x_kv in one dispatch
  conv_stage1<<<4 * (nW8 / 256) + nX8 / 256, 256, 0, stream>>>(
      Wk, Wv, Wq, Wo, x_kv, Wk_b, Wo_b, Sx);

  // Fused K+V projection: B = [Wk_b ; Wv_b] (contiguous), N = 2048.
  gemm128<3><<<dim3(2 * DM / 128, MROWS / 128), 256, 0, stream>>>(
      Sx, Wk_b, kb, vtb, MROWS, 2 * DM, DM);
  conv_f32_bf16<<<nX8 / 256, 256, 0, stream>>>(x_q, Sx, nX8);
  // Q projection with QSCALE folded into the epilogue (MODE 4).
  gemm128<4><<<dim3(DM / 128, MROWS / 128), 256, 0, stream>>>(
      Sx, Wq_b, qb, nullptr, MROWS, DM, DM);
  attn_flash2<<<dim3(8, NH, BB), 256, 0, stream>>>(qb, kb, vtb, qb);
  gemm128<1><<<dim3(DM / 128, MROWS / 128), 256, 0, stream>>>(
      qb, Wo_b, out, nullptr, MROWS, DM, DM);
}